// Round 7
// baseline (400.794 us; speedup 1.0000x reference)
//
#include <hip/hip_runtime.h>
#include <stdint.h>

// Problem sizes (fixed by the reference)
#define NQn 131072
#define NCn 65536
#define En  1048576
// D = 128, HID = 256

typedef __bf16 bf16;
typedef __bf16 bf16x2 __attribute__((ext_vector_type(2)));
typedef __bf16 bf16x4 __attribute__((ext_vector_type(4)));
typedef __bf16 bf16x8 __attribute__((ext_vector_type(8)));
typedef float  f32x4  __attribute__((ext_vector_type(4)));

// ---------------------------------------------------------------------------
// Weight transpose + bf16 cast: Wt[m*K+k] = bf16(W[k*M+m])
// ---------------------------------------------------------------------------
__global__ void wtrans_all(
    const float* __restrict__ w0, bf16* __restrict__ t0,
    const float* __restrict__ w1, bf16* __restrict__ t1,
    const float* __restrict__ w2, bf16* __restrict__ t2,
    const float* __restrict__ w3, bf16* __restrict__ t3,
    const float* __restrict__ w4, bf16* __restrict__ t4,
    const float* __restrict__ w5, bf16* __restrict__ t5,
    const float* __restrict__ w6, bf16* __restrict__ t6,
    const float* __restrict__ w7, bf16* __restrict__ t7) {
  const float* W; bf16* T; int K, M;
  switch (blockIdx.y) {
    case 0: W = w0; T = t0; K = 128; M = 128; break;  // Wres_Q
    case 1: W = w1; T = t1; K = 128; M = 128; break;  // Wres_C
    case 2: W = w2; T = t2; K = 128; M = 128; break;  // Wrel_QC
    case 3: W = w3; T = t3; K = 128; M = 128; break;  // Wrel_CQ
    case 4: W = w4; T = t4; K = 256; M = 256; break;  // W1_Q
    case 5: W = w5; T = t5; K = 256; M = 256; break;  // W1_C
    case 6: W = w6; T = t6; K = 256; M = 128; break;  // W2_Q
    default: W = w7; T = t7; K = 256; M = 128; break; // W2_C
  }
  int t = blockIdx.x * 256 + threadIdx.x;
  if (t >= K * M) return;
  int m = t % M, k = t / M;
  T[m * K + k] = (bf16)W[k * M + m];
}

// ---------------------------------------------------------------------------
// 128x128-tile bf16 MFMA GEMM, A staged in LDS (32 KB, XOR-swizzled),
// B fragments loaded per-wave directly from global (weights are L2-hot).
// ASRC: 0 bf16 input; 1 f32 input (cast); 2 f32 input + fused LayerNorm.
// EPI:  0 store bf16; 1 row-scale store bf16; 2 +bias tanh-GELU store bf16;
//       3 +bias +resid store f32.
// ---------------------------------------------------------------------------
#define ASRC_BF16 0
#define ASRC_F32  1
#define ASRC_LN   2
#define EPI_BF16  0
#define EPI_RSCL  1
#define EPI_GELU  2
#define EPI_RES   3

template <int ASRC, int EPI, int NK>
__global__ __launch_bounds__(256, 3) void gemm_kernel(
    const void* __restrict__ A0, const void* __restrict__ A1,
    const bf16* __restrict__ Bt, const float* __restrict__ bias,
    const float* __restrict__ rowscale, const bf16* __restrict__ resid,
    const float* __restrict__ lng, const float* __restrict__ lnbp,
    bf16* __restrict__ outB, float* __restrict__ outF,
    int ldA, int kOff, int ldOut) {
  __shared__ __align__(16) unsigned char lds[32768];
  const int tid = threadIdx.x;
  const int row0 = blockIdx.x * 128;
  const int col0 = blockIdx.y * 128;
  const int wid = tid >> 6, lane = tid & 63;
  const int wrow = (wid >> 1) * 64, wcol = (wid & 1) * 64;

  f32x4 acc[4][4] = {};

  #pragma unroll
  for (int kc = 0; kc < NK; ++kc) {
    if (kc) __syncthreads();
    const void* ap = (kc == 0) ? A0 : A1;
    const int kofs = kc * kOff;
    if (ASRC == ASRC_F32) {
      const float* Af = (const float*)ap;
      #pragma unroll
      for (int it = 0; it < 16; ++it) {
        int lin = it * 256 + tid;
        int r = lin >> 5;
        int c = (lin & 31) * 4;
        float4 v = *(const float4*)(Af + (size_t)(row0 + r) * ldA + kofs + c);
        bf16x4 w;
        w[0] = (bf16)v.x; w[1] = (bf16)v.y; w[2] = (bf16)v.z; w[3] = (bf16)v.w;
        *(bf16x4*)(lds + r * 256 + ((c * 2) ^ ((r & 7) << 4))) = w;
      }
    } else if (ASRC == ASRC_LN) {
      const float* Af = (const float*)ap;
      #pragma unroll
      for (int it = 0; it < 16; ++it) {
        int lin = it * 256 + tid;
        int r = lin >> 5;
        int c = (lin & 31) * 4;
        float4 v = *(const float4*)(Af + (size_t)(row0 + r) * 128 + c);
        float s = v.x + v.y + v.z + v.w;
        #pragma unroll
        for (int o = 16; o; o >>= 1) s += __shfl_xor(s, o, 64);
        float mean = s * (1.0f / 128.0f);
        float d0 = v.x - mean, d1 = v.y - mean, d2 = v.z - mean, d3 = v.w - mean;
        float q = d0 * d0 + d1 * d1 + d2 * d2 + d3 * d3;
        #pragma unroll
        for (int o = 16; o; o >>= 1) q += __shfl_xor(q, o, 64);
        float rsv = rsqrtf(q * (1.0f / 128.0f) + 1e-5f);
        float4 gg = *(const float4*)(lng + c);
        float4 bb = *(const float4*)(lnbp + c);
        bf16x4 w;
        w[0] = (bf16)(d0 * rsv * gg.x + bb.x);
        w[1] = (bf16)(d1 * rsv * gg.y + bb.y);
        w[2] = (bf16)(d2 * rsv * gg.z + bb.z);
        w[3] = (bf16)(d3 * rsv * gg.w + bb.w);
        *(bf16x4*)(lds + r * 256 + ((c * 2) ^ ((r & 7) << 4))) = w;
      }
    } else {
      const bf16* Ab = (const bf16*)ap;
      #pragma unroll
      for (int it = 0; it < 8; ++it) {
        int lin = it * 256 + tid;
        int r = lin >> 4;
        int cb = (lin & 15) * 16;
        bf16x8 v = *(const bf16x8*)((const char*)Ab +
                    ((size_t)(row0 + r) * ldA + kofs) * 2 + cb);
        *(bf16x8*)(lds + r * 256 + (cb ^ ((r & 7) << 4))) = v;
      }
    }
    __syncthreads();
    #pragma unroll
    for (int kk = 0; kk < 4; ++kk) {
      bf16x8 af[4], bfv[4];
      const int kb = kk * 64 + (lane >> 4) * 16;   // BYTE offset within 256B k-row
      #pragma unroll
      for (int fc = 0; fc < 4; ++fc) {
        int br = col0 + wcol + fc * 16 + (lane & 15);
        // element offset = kb>>1  (bug fix from R6: kb is bytes, Bt+ is elements)
        bfv[fc] = *(const bf16x8*)(Bt + (size_t)br * (NK * 128) + kc * 128 + (kb >> 1));
      }
      #pragma unroll
      for (int fr = 0; fr < 4; ++fr) {
        int ar = wrow + fr * 16 + (lane & 15);
        af[fr] = *(const bf16x8*)(lds + ar * 256 + (kb ^ ((ar & 7) << 4)));
      }
      #pragma unroll
      for (int fr = 0; fr < 4; ++fr)
        #pragma unroll
        for (int fc = 0; fc < 4; ++fc)
          acc[fr][fc] = __builtin_amdgcn_mfma_f32_16x16x32_bf16(
              af[fr], bfv[fc], acc[fr][fc], 0, 0, 0);
    }
  }

  const int rbase = row0 + wrow + (lane >> 4) * 4;
  const int cbase = col0 + wcol + (lane & 15);
  #pragma unroll
  for (int fr = 0; fr < 4; ++fr) {
    float rs[4];
    if (EPI == EPI_RSCL) {
      #pragma unroll
      for (int r = 0; r < 4; ++r) {
        float dv = rowscale[rbase + fr * 16 + r];
        rs[r] = dv > 0.f ? rsqrtf(dv) : 0.f;
      }
    }
    #pragma unroll
    for (int fc = 0; fc < 4; ++fc) {
      const int col = cbase + fc * 16;
      float bv = (EPI == EPI_GELU || EPI == EPI_RES) ? bias[col] : 0.f;
      #pragma unroll
      for (int r = 0; r < 4; ++r) {
        const int row = rbase + fr * 16 + r;
        float x = acc[fr][fc][r];
        if (EPI == EPI_BF16) {
          outB[(size_t)row * ldOut + col] = (bf16)x;
        } else if (EPI == EPI_RSCL) {
          outB[(size_t)row * ldOut + col] = (bf16)(x * rs[r]);
        } else if (EPI == EPI_GELU) {
          x += bv;
          float u2 = 1.5957691216057308f * (x + 0.044715f * x * x * x);
          float e = __expf(u2);
          float th = 1.f - 2.f / (e + 1.f);
          x = 0.5f * x * (1.f + th);
          outB[(size_t)row * ldOut + col] = (bf16)x;
        } else {
          x += bv + (float)resid[(size_t)row * 128 + col];
          outF[(size_t)row * 128 + col] = x;
        }
      }
    }
  }
}

// ---------------------------------------------------------------------------
// Bucket histogram from deg (bucket = 128 dst rows). One wave per bucket.
// bcnt layout: [512 QC][1024 CQ]
// ---------------------------------------------------------------------------
__global__ __launch_bounds__(256) void bucket_hist(
    const float* __restrict__ degQC, const float* __restrict__ degCQ,
    int* __restrict__ bcnt) {
  int w = (blockIdx.x * 256 + threadIdx.x) >> 6;
  int lane = threadIdx.x & 63;
  const float* deg = (w < 512) ? (degQC + (size_t)w * 128)
                               : (degCQ + (size_t)(w - 512) * 128);
  float s = deg[lane] + deg[lane + 64];
  #pragma unroll
  for (int o = 32; o; o >>= 1) s += __shfl_xor(s, o, 64);
  if (lane == 0) bcnt[w] = (int)(s + 0.5f);
}

// Single-block exclusive scan over both bucket-count arrays -> bases + cursors.
__global__ __launch_bounds__(1024) void bucket_scan(
    const int* __restrict__ bcnt,
    int* __restrict__ baseQC, int* __restrict__ gcurQC,
    int* __restrict__ baseCQ, int* __restrict__ gcurCQ) {
  __shared__ int ss[1024];
  const int t = threadIdx.x;
  int v = (t < 512) ? bcnt[t] : 0;
  ss[t] = v;
  __syncthreads();
  for (int o = 1; o < 1024; o <<= 1) {
    int x = (t >= o) ? ss[t - o] : 0;
    __syncthreads();
    ss[t] += x;
    __syncthreads();
  }
  if (t < 512) { int e = ss[t] - v; baseQC[t] = e; gcurQC[t] = e; }
  if (t == 0) baseQC[512] = En;
  __syncthreads();
  int v2 = bcnt[512 + t];
  ss[t] = v2;
  __syncthreads();
  for (int o = 1; o < 1024; o <<= 1) {
    int x = (t >= o) ? ss[t - o] : 0;
    __syncthreads();
    ss[t] += x;
    __syncthreads();
  }
  { int e = ss[t] - v2; baseCQ[t] = e; gcurCQ[t] = e; }
  if (t == 0) baseCQ[1024] = En;
}

// ---------------------------------------------------------------------------
// Pass A: partition (src,dst) pairs into bucket-grouped ebuf (bucket=dst>>7).
// ---------------------------------------------------------------------------
#define CHUNK 4096

template <int NB>
__global__ __launch_bounds__(256) void bucketA(
    const int* __restrict__ esrc, const int* __restrict__ edst,
    int* __restrict__ gcur, uint2* __restrict__ ebuf) {
  __shared__ int lcount[NB], lexcl[NB], lbase[NB], lofs[NB];
  __shared__ int ss[256];
  __shared__ uint2 stage[CHUNK];
  const int t = threadIdx.x;
  for (int b = t; b < NB; b += 256) lcount[b] = 0;
  __syncthreads();
  const int e0 = blockIdx.x * CHUNK;
  uint2 ed[16];
  #pragma unroll
  for (int j = 0; j < 16; ++j) {
    int e = e0 + j * 256 + t;
    ed[j].x = (unsigned)esrc[e];
    ed[j].y = (unsigned)edst[e];
    atomicAdd(&lcount[ed[j].y >> 7], 1);
  }
  __syncthreads();
  constexpr int R = NB / 256;
  int c[R]; int mysum = 0;
  #pragma unroll
  for (int j = 0; j < R; ++j) { c[j] = lcount[t * R + j]; mysum += c[j]; }
  ss[t] = mysum;
  __syncthreads();
  for (int o = 1; o < 256; o <<= 1) {
    int x = (t >= o) ? ss[t - o] : 0;
    __syncthreads();
    ss[t] += x;
    __syncthreads();
  }
  int run = ss[t] - mysum;
  #pragma unroll
  for (int j = 0; j < R; ++j) { lexcl[t * R + j] = run; run += c[j]; }
  __syncthreads();
  for (int b = t; b < NB; b += 256) {
    lbase[b] = atomicAdd(&gcur[b], lcount[b]);
    lofs[b]  = lexcl[b];
  }
  __syncthreads();
  #pragma unroll
  for (int j = 0; j < 16; ++j) {
    int b = ed[j].y >> 7;
    int p = atomicAdd(&lofs[b], 1);
    stage[p] = ed[j];
  }
  __syncthreads();
  for (int i = t; i < CHUNK; i += 256) {
    uint2 v = stage[i];
    int b = v.y >> 7;
    ebuf[lbase[b] + (i - lexcl[b])] = v;
  }
}

// ---------------------------------------------------------------------------
// bucketB2: per 128-dst bucket: local deg-scan -> offs; fill csr window via
// native INT LDS atomics (fast). csr window is contiguous per block (L2-hot).
// ---------------------------------------------------------------------------
__global__ __launch_bounds__(256) void bucketB2(
    const uint2* __restrict__ ebuf, const int* __restrict__ bbase,
    const float* __restrict__ degdst, int* __restrict__ offs,
    int* __restrict__ csr) {
  __shared__ int sdeg[128];
  __shared__ int lcur[128];
  const int b = blockIdx.x;
  const int t = threadIdx.x;
  const int base = bbase[b], end = bbase[b + 1];
  int myv = 0;
  if (t < 128) {
    myv = (int)(degdst[(size_t)b * 128 + t] + 0.5f);
    sdeg[t] = myv;
  }
  __syncthreads();
  for (int o = 1; o < 128; o <<= 1) {
    int x = (t < 128 && t >= o) ? sdeg[t - o] : 0;
    __syncthreads();
    if (t < 128) sdeg[t] += x;
    __syncthreads();
  }
  if (t < 128) {
    int excl = sdeg[t] - myv;
    lcur[t] = excl;
    offs[(size_t)b * 128 + t] = base + excl;
  }
  __syncthreads();
  for (int i = base + t; i < end; i += 256) {
    uint2 v = ebuf[i];
    int p = atomicAdd(&lcur[v.y & 127], 1);
    csr[base + p] = (int)v.x;
  }
}

// ---------------------------------------------------------------------------
// gather2: one wave per dst row, half-wave pairing; 8 edges in flight.
// ---------------------------------------------------------------------------
__global__ __launch_bounds__(256) void gather2(
    const bf16* __restrict__ Xn, const int* __restrict__ csr,
    const int* __restrict__ offs, const float* __restrict__ degdst,
    const float* __restrict__ gate, bf16* __restrict__ msg, int ndst) {
  int d = blockIdx.x * 4 + (threadIdx.x >> 6);
  if (d >= ndst) return;
  int lane = threadIdx.x & 63;
  int half = lane >> 5, sl = lane & 31;
  float dv = degdst[d];
  int cnt = (int)(dv + 0.5f);
  int start = offs[d];
  float a0 = 0.f, a1 = 0.f, a2 = 0.f, a3 = 0.f;
  int i = 0;
  for (; i + 8 <= cnt; i += 8) {
    int s0 = csr[start + i + half * 4 + 0];
    int s1 = csr[start + i + half * 4 + 1];
    int s2 = csr[start + i + half * 4 + 2];
    int s3 = csr[start + i + half * 4 + 3];
    bf16x4 v0 = *(const bf16x4*)(Xn + (size_t)s0 * 128 + sl * 4);
    bf16x4 v1 = *(const bf16x4*)(Xn + (size_t)s1 * 128 + sl * 4);
    bf16x4 v2 = *(const bf16x4*)(Xn + (size_t)s2 * 128 + sl * 4);
    bf16x4 v3 = *(const bf16x4*)(Xn + (size_t)s3 * 128 + sl * 4);
    a0 += (float)v0[0] + (float)v1[0] + (float)v2[0] + (float)v3[0];
    a1 += (float)v0[1] + (float)v1[1] + (float)v2[1] + (float)v3[1];
    a2 += (float)v0[2] + (float)v1[2] + (float)v2[2] + (float)v3[2];
    a3 += (float)v0[3] + (float)v1[3] + (float)v2[3] + (float)v3[3];
  }
  for (; i + 2 <= cnt; i += 2) {
    int s0 = csr[start + i + half];
    bf16x4 v0 = *(const bf16x4*)(Xn + (size_t)s0 * 128 + sl * 4);
    a0 += (float)v0[0]; a1 += (float)v0[1];
    a2 += (float)v0[2]; a3 += (float)v0[3];
  }
  if (i < cnt && half == 0) {
    int s0 = csr[start + i];
    bf16x4 v0 = *(const bf16x4*)(Xn + (size_t)s0 * 128 + sl * 4);
    a0 += (float)v0[0]; a1 += (float)v0[1];
    a2 += (float)v0[2]; a3 += (float)v0[3];
  }
  a0 += __shfl_xor(a0, 32, 64);
  a1 += __shfl_xor(a1, 32, 64);
  a2 += __shfl_xor(a2, 32, 64);
  a3 += __shfl_xor(a3, 32, 64);
  if (half == 0) {
    float sc = (dv > 0.f ? rsqrtf(dv) : 0.f) * gate[0];
    bf16x4 r;
    r[0] = (bf16)(a0 * sc); r[1] = (bf16)(a1 * sc);
    r[2] = (bf16)(a2 * sc); r[3] = (bf16)(a3 * sc);
    *(bf16x4*)(msg + (size_t)d * 128 + sl * 4) = r;
  }
}

// ---------------------------------------------------------------------------
extern "C" void kernel_launch(void* const* d_in, const int* in_sizes, int n_in,
                              void* d_out, int out_size, void* d_ws, size_t ws_size,
                              hipStream_t stream) {
  const float* H_Q        = (const float*)d_in[0];
  const float* H_C        = (const float*)d_in[1];
  const int*   eQC_src    = (const int*)d_in[2];
  const int*   eQC_dst    = (const int*)d_in[3];
  const int*   eCQ_src    = (const int*)d_in[4];
  const int*   eCQ_dst    = (const int*)d_in[5];
  const float* deg_QC_src = (const float*)d_in[6];
  const float* deg_QC_dst = (const float*)d_in[7];
  const float* deg_CQ_src = (const float*)d_in[8];
  const float* deg_CQ_dst = (const float*)d_in[9];
  const float* ln_g_Q     = (const float*)d_in[10];
  const float* ln_b_Q     = (const float*)d_in[11];
  const float* Wres_Q     = (const float*)d_in[12];
  const float* ln_g_C     = (const float*)d_in[13];
  const float* ln_b_C     = (const float*)d_in[14];
  const float* Wres_C     = (const float*)d_in[15];
  const float* Wrel_QC    = (const float*)d_in[16];
  const float* Wrel_CQ    = (const float*)d_in[17];
  const float* gate_QC    = (const float*)d_in[18];
  const float* gate_CQ    = (const float*)d_in[19];
  const float* W1_Q       = (const float*)d_in[20];
  const float* b1_Q       = (const float*)d_in[21];
  const float* W2_Q       = (const float*)d_in[22];
  const float* b2_Q       = (const float*)d_in[23];
  const float* W1_C       = (const float*)d_in[24];
  const float* b1_C       = (const float*)d_in[25];
  const float* W2_C       = (const float*)d_in[26];
  const float* b2_C       = (const float*)d_in[27];

  char* ws = (char*)d_ws;
  size_t o = 0;
  auto alloc = [&](size_t bytes) -> char* {
    char* p = ws + o;
    o += (bytes + 255) & ~(size_t)255;
    return p;
  };
  // R0 overlay timeline:
  //   phase A (GEMMs/gather): [xnbQ 32MB][xnbC 16MB][csrQC 8MB][csrCQ 8MB][..]
  //   phase B (MLP):          [hQ 64MB][hC 32MB]
  char* r0 = alloc(100663296);
  bf16* xnbQ = (bf16*)r0;
  bf16* xnbC = (bf16*)(r0 + 33554432);
  int*  csrQC = (int*)(r0 + 50331648);
  int*  csrCQ = (int*)(r0 + 58720256);
  bf16* hQ   = (bf16*)r0;
  bf16* hC   = (bf16*)(r0 + 67108864);
  bf16* projQ = (bf16*)alloc((size_t)NQn * 128 * 2);
  bf16* projC = (bf16*)alloc((size_t)NCn * 128 * 2);
  bf16* msgQ  = (bf16*)alloc((size_t)NQn * 128 * 2);
  bf16* msgC  = (bf16*)alloc((size_t)NCn * 128 * 2);
  uint2* ebufQC = (uint2*)alloc((size_t)En * 8);
  uint2* ebufCQ = (uint2*)alloc((size_t)En * 8);
  bf16* WresQt = (bf16*)alloc(128 * 128 * 2);
  bf16* WresCt = (bf16*)alloc(128 * 128 * 2);
  bf16* WrelQCt = (bf16*)alloc(128 * 128 * 2);
  bf16* WrelCQt = (bf16*)alloc(128 * 128 * 2);
  bf16* W1Qt = (bf16*)alloc(256 * 256 * 2);
  bf16* W1Ct = (bf16*)alloc(256 * 256 * 2);
  bf16* W2Qt = (bf16*)alloc(128 * 256 * 2);
  bf16* W2Ct = (bf16*)alloc(128 * 256 * 2);
  int* bcnt   = (int*)alloc(1536 * 4);
  int* bbaseQC = (int*)alloc(513 * 4);
  int* bbaseCQ = (int*)alloc(1025 * 4);
  int* gcurQC = (int*)alloc(512 * 4);
  int* gcurCQ = (int*)alloc(1024 * 4);
  int* offsQC = (int*)alloc((size_t)NCn * 4);
  int* offsCQ = (int*)alloc((size_t)NQn * 4);

  float* outQ = (float*)d_out;
  float* outC = (float*)d_out + (size_t)NQn * 128;

  // 1. weight transpose+cast
  wtrans_all<<<dim3(256, 8), 256, 0, stream>>>(
      Wres_Q, WresQt, Wres_C, WresCt, Wrel_QC, WrelQCt, Wrel_CQ, WrelCQt,
      W1_Q, W1Qt, W1_C, W1Ct, W2_Q, W2Qt, W2_C, W2Ct);

  // 2. bucket bases + edge partition + CSR build
  bucket_hist<<<384, 256, 0, stream>>>(deg_QC_dst, deg_CQ_dst, bcnt);
  bucket_scan<<<1, 1024, 0, stream>>>(bcnt, bbaseQC, gcurQC, bbaseCQ, gcurCQ);
  bucketA<512><<<En / CHUNK, 256, 0, stream>>>(eQC_src, eQC_dst, gcurQC, ebufQC);
  bucketA<1024><<<En / CHUNK, 256, 0, stream>>>(eCQ_src, eCQ_dst, gcurCQ, ebufCQ);
  bucketB2<<<512, 256, 0, stream>>>(ebufQC, bbaseQC, deg_QC_dst, offsQC, csrQC);
  bucketB2<<<1024, 256, 0, stream>>>(ebufCQ, bbaseCQ, deg_CQ_dst, offsCQ, csrCQ);

  // 3. proj = LN(H) @ Wres  (LN fused into A-staging, bf16 out)
  gemm_kernel<ASRC_LN, EPI_BF16, 1><<<dim3(NQn / 128, 1), 256, 0, stream>>>(
      H_Q, nullptr, WresQt, nullptr, nullptr, nullptr, ln_g_Q, ln_b_Q,
      projQ, nullptr, 128, 0, 128);
  gemm_kernel<ASRC_LN, EPI_BF16, 1><<<dim3(NCn / 128, 1), 256, 0, stream>>>(
      H_C, nullptr, WresCt, nullptr, nullptr, nullptr, ln_g_C, ln_b_C,
      projC, nullptr, 128, 0, 128);

  // 4. Xn = (H @ Wrel) * invsqrt(deg_src)  (bf16 out)
  gemm_kernel<ASRC_F32, EPI_RSCL, 1><<<dim3(NQn / 128, 1), 256, 0, stream>>>(
      H_Q, nullptr, WrelQCt, nullptr, deg_QC_src, nullptr, nullptr, nullptr,
      xnbQ, nullptr, 128, 0, 128);
  gemm_kernel<ASRC_F32, EPI_RSCL, 1><<<dim3(NCn / 128, 1), 256, 0, stream>>>(
      H_C, nullptr, WrelCQt, nullptr, deg_CQ_src, nullptr, nullptr, nullptr,
      xnbC, nullptr, 128, 0, 128);

  // 5. gather (scatter-free SpMM): msgC from xnbQ (QC), msgQ from xnbC (CQ)
  gather2<<<NCn / 4, 256, 0, stream>>>(xnbQ, csrQC, offsQC, deg_QC_dst,
                                       gate_QC, msgC, NCn);
  gather2<<<NQn / 4, 256, 0, stream>>>(xnbC, csrCQ, offsCQ, deg_CQ_dst,
                                       gate_CQ, msgQ, NQn);

  // 6. MLP layer 1: h = gelu([proj | msg] @ W1 + b1)  (writes over R0 — xnb/csr dead)
  gemm_kernel<ASRC_BF16, EPI_GELU, 2><<<dim3(NQn / 128, 2), 256, 0, stream>>>(
      projQ, msgQ, W1Qt, b1_Q, nullptr, nullptr, nullptr, nullptr,
      hQ, nullptr, 128, 0, 256);
  gemm_kernel<ASRC_BF16, EPI_GELU, 2><<<dim3(NCn / 128, 2), 256, 0, stream>>>(
      projC, msgC, W1Ct, b1_C, nullptr, nullptr, nullptr, nullptr,
      hC, nullptr, 128, 0, 256);

  // 7. MLP layer 2 + residual: out = proj + h @ W2 + b2  (f32 out)
  gemm_kernel<ASRC_BF16, EPI_RES, 2><<<dim3(NQn / 128, 1), 256, 0, stream>>>(
      hQ, hQ, W2Qt, b2_Q, nullptr, projQ, nullptr, nullptr,
      nullptr, outQ, 256, 128, 128);
  gemm_kernel<ASRC_BF16, EPI_RES, 2><<<dim3(NCn / 128, 1), 256, 0, stream>>>(
      hC, hC, W2Ct, b2_C, nullptr, projC, nullptr, nullptr,
      nullptr, outC, 256, 128, 128);
}

// Round 8
// 363.690 us; speedup vs baseline: 1.1020x; 1.1020x over previous
//
#include <hip/hip_runtime.h>
#include <stdint.h>

// Problem sizes (fixed by the reference)
#define NQn 131072
#define NCn 65536
#define En  1048576
// D = 128, HID = 256

typedef __bf16 bf16;
typedef __bf16 bf16x2 __attribute__((ext_vector_type(2)));
typedef __bf16 bf16x4 __attribute__((ext_vector_type(4)));
typedef __bf16 bf16x8 __attribute__((ext_vector_type(8)));
typedef float  f32x4  __attribute__((ext_vector_type(4)));

// ---------------------------------------------------------------------------
// Weight transpose + bf16 cast: Wt[m*K+k] = bf16(W[k*M+m])
// ---------------------------------------------------------------------------
__global__ void wtrans_all(
    const float* __restrict__ w0, bf16* __restrict__ t0,
    const float* __restrict__ w1, bf16* __restrict__ t1,
    const float* __restrict__ w2, bf16* __restrict__ t2,
    const float* __restrict__ w3, bf16* __restrict__ t3,
    const float* __restrict__ w4, bf16* __restrict__ t4,
    const float* __restrict__ w5, bf16* __restrict__ t5,
    const float* __restrict__ w6, bf16* __restrict__ t6,
    const float* __restrict__ w7, bf16* __restrict__ t7) {
  const float* W; bf16* T; int K, M;
  switch (blockIdx.y) {
    case 0: W = w0; T = t0; K = 128; M = 128; break;  // Wres_Q
    case 1: W = w1; T = t1; K = 128; M = 128; break;  // Wres_C
    case 2: W = w2; T = t2; K = 128; M = 128; break;  // Wrel_QC
    case 3: W = w3; T = t3; K = 128; M = 128; break;  // Wrel_CQ
    case 4: W = w4; T = t4; K = 256; M = 256; break;  // W1_Q
    case 5: W = w5; T = t5; K = 256; M = 256; break;  // W1_C
    case 6: W = w6; T = t6; K = 256; M = 128; break;  // W2_Q
    default: W = w7; T = t7; K = 256; M = 128; break; // W2_C
  }
  int t = blockIdx.x * 256 + threadIdx.x;
  if (t >= K * M) return;
  int m = t % M, k = t / M;
  T[m * K + k] = (bf16)W[k * M + m];
}

// ---------------------------------------------------------------------------
// dual_gemm: one H read -> proj = LN(H)@Wres (bf16) AND xn = (H@Wrel)*deg^-1/2.
// 256 threads / 4 waves; LDS: lnh panel [128][128] bf16 @0, hb panel @32768.
// ---------------------------------------------------------------------------
__global__ __launch_bounds__(256, 2) void dual_gemm(
    const float* __restrict__ H, const float* __restrict__ lng,
    const float* __restrict__ lnb, const bf16* __restrict__ Wres,
    const bf16* __restrict__ Wrel, const float* __restrict__ degsrc,
    bf16* __restrict__ proj, bf16* __restrict__ xn) {
  __shared__ __align__(16) unsigned char lds[65536];
  const int tid = threadIdx.x;
  const int row0 = blockIdx.x * 128;
  const int wid = tid >> 6, lane = tid & 63;
  const int wrow = (wid >> 1) * 64, wcol = (wid & 1) * 64;

  // stage: read H f32, compute LN inline (32 tids per row), write both panels
  #pragma unroll
  for (int it = 0; it < 16; ++it) {
    int lin = it * 256 + tid;
    int r = lin >> 5;
    int c = (lin & 31) * 4;
    float4 v = *(const float4*)(H + (size_t)(row0 + r) * 128 + c);
    float s = v.x + v.y + v.z + v.w;
    #pragma unroll
    for (int o = 16; o; o >>= 1) s += __shfl_xor(s, o, 64);
    float mean = s * (1.0f / 128.0f);
    float d0 = v.x - mean, d1 = v.y - mean, d2 = v.z - mean, d3 = v.w - mean;
    float q = d0 * d0 + d1 * d1 + d2 * d2 + d3 * d3;
    #pragma unroll
    for (int o = 16; o; o >>= 1) q += __shfl_xor(q, o, 64);
    float rsv = rsqrtf(q * (1.0f / 128.0f) + 1e-5f);
    float4 gg = *(const float4*)(lng + c);
    float4 bb = *(const float4*)(lnb + c);
    bf16x4 w;
    w[0] = (bf16)(d0 * rsv * gg.x + bb.x);
    w[1] = (bf16)(d1 * rsv * gg.y + bb.y);
    w[2] = (bf16)(d2 * rsv * gg.z + bb.z);
    w[3] = (bf16)(d3 * rsv * gg.w + bb.w);
    int off = r * 256 + ((c * 2) ^ ((r & 7) << 4));
    *(bf16x4*)(lds + off) = w;
    bf16x4 rw;
    rw[0] = (bf16)v.x; rw[1] = (bf16)v.y; rw[2] = (bf16)v.z; rw[3] = (bf16)v.w;
    *(bf16x4*)(lds + 32768 + off) = rw;
  }
  __syncthreads();

  // GEMM 1: proj = lnh @ Wres
  {
    f32x4 acc[4][4] = {};
    #pragma unroll
    for (int kk = 0; kk < 4; ++kk) {
      const int kb = kk * 64 + (lane >> 4) * 16;
      bf16x8 af[4], bfv[4];
      #pragma unroll
      for (int fc = 0; fc < 4; ++fc) {
        int br = wcol + fc * 16 + (lane & 15);
        bfv[fc] = *(const bf16x8*)(Wres + (size_t)br * 128 + (kb >> 1));
      }
      #pragma unroll
      for (int fr = 0; fr < 4; ++fr) {
        int ar = wrow + fr * 16 + (lane & 15);
        af[fr] = *(const bf16x8*)(lds + ar * 256 + (kb ^ ((ar & 7) << 4)));
      }
      #pragma unroll
      for (int fr = 0; fr < 4; ++fr)
        #pragma unroll
        for (int fc = 0; fc < 4; ++fc)
          acc[fr][fc] = __builtin_amdgcn_mfma_f32_16x16x32_bf16(
              af[fr], bfv[fc], acc[fr][fc], 0, 0, 0);
    }
    const int rbase = row0 + wrow + (lane >> 4) * 4;
    const int cbase = wcol + (lane & 15);
    #pragma unroll
    for (int fr = 0; fr < 4; ++fr)
      #pragma unroll
      for (int fc = 0; fc < 4; ++fc)
        #pragma unroll
        for (int r = 0; r < 4; ++r)
          proj[(size_t)(rbase + fr * 16 + r) * 128 + cbase + fc * 16] =
              (bf16)acc[fr][fc][r];
  }

  // GEMM 2: xn = (hb @ Wrel) * invsqrt(deg_src)
  {
    f32x4 acc[4][4] = {};
    #pragma unroll
    for (int kk = 0; kk < 4; ++kk) {
      const int kb = kk * 64 + (lane >> 4) * 16;
      bf16x8 af[4], bfv[4];
      #pragma unroll
      for (int fc = 0; fc < 4; ++fc) {
        int br = wcol + fc * 16 + (lane & 15);
        bfv[fc] = *(const bf16x8*)(Wrel + (size_t)br * 128 + (kb >> 1));
      }
      #pragma unroll
      for (int fr = 0; fr < 4; ++fr) {
        int ar = wrow + fr * 16 + (lane & 15);
        af[fr] = *(const bf16x8*)(lds + 32768 + ar * 256 + (kb ^ ((ar & 7) << 4)));
      }
      #pragma unroll
      for (int fr = 0; fr < 4; ++fr)
        #pragma unroll
        for (int fc = 0; fc < 4; ++fc)
          acc[fr][fc] = __builtin_amdgcn_mfma_f32_16x16x32_bf16(
              af[fr], bfv[fc], acc[fr][fc], 0, 0, 0);
    }
    const int rbase = row0 + wrow + (lane >> 4) * 4;
    const int cbase = wcol + (lane & 15);
    #pragma unroll
    for (int fr = 0; fr < 4; ++fr) {
      float rs[4];
      #pragma unroll
      for (int r = 0; r < 4; ++r) {
        float dv = degsrc[rbase + fr * 16 + r];
        rs[r] = dv > 0.f ? rsqrtf(dv) : 0.f;
      }
      #pragma unroll
      for (int fc = 0; fc < 4; ++fc)
        #pragma unroll
        for (int r = 0; r < 4; ++r)
          xn[(size_t)(rbase + fr * 16 + r) * 128 + cbase + fc * 16] =
              (bf16)(acc[fr][fc][r] * rs[r]);
    }
  }
}

// ---------------------------------------------------------------------------
// mlp_fused: out = proj + GELU([proj|msg]@W1+b1)@W2 + b2, one kernel.
// 512 threads / 8 waves. LDS 64KB: panels P,M (phase 1) then h[128][256] (ph 2).
// ---------------------------------------------------------------------------
__global__ __launch_bounds__(512, 4) void mlp_fused(
    const bf16* __restrict__ proj, const bf16* __restrict__ msg,
    const bf16* __restrict__ W1t, const float* __restrict__ b1,
    const bf16* __restrict__ W2t, const float* __restrict__ b2,
    float* __restrict__ out) {
  __shared__ __align__(16) unsigned char lds[65536];
  const int tid = threadIdx.x;
  const int row0 = blockIdx.x * 128;
  const int wid = tid >> 6, lane = tid & 63;

  // stage proj -> panel P (0..32K), msg -> panel M (32K..64K); rows 256B
  #pragma unroll
  for (int it = 0; it < 4; ++it) {
    int lin = it * 512 + tid;      // 0..2047
    int r = lin >> 4;
    int cb = (lin & 15) * 16;
    int off = r * 256 + (cb ^ ((r & 7) << 4));
    bf16x8 vp = *(const bf16x8*)((const char*)proj +
                 ((size_t)(row0 + r) * 128) * 2 + cb);
    *(bf16x8*)(lds + off) = vp;
    bf16x8 vm = *(const bf16x8*)((const char*)msg +
                 ((size_t)(row0 + r) * 128) * 2 + cb);
    *(bf16x8*)(lds + 32768 + off) = vm;
  }
  __syncthreads();

  // phase 1: h = A @ W1  (A=[P|M], K=256); wave grid 2 rows x 4 cols of 64
  const int wr = wid >> 2;
  const int wc = wid & 3;
  f32x4 acc1[4][4] = {};
  #pragma unroll
  for (int kk = 0; kk < 8; ++kk) {
    const unsigned pbase = (kk < 4) ? 0u : 32768u;
    const int kb = (kk & 3) * 64 + (lane >> 4) * 16;
    bf16x8 af[4], bfv[4];
    #pragma unroll
    for (int fc = 0; fc < 4; ++fc) {
      int br = wc * 64 + fc * 16 + (lane & 15);
      bfv[fc] = *(const bf16x8*)(W1t + (size_t)br * 256 + kk * 32 + (lane >> 4) * 8);
    }
    #pragma unroll
    for (int fr = 0; fr < 4; ++fr) {
      int ar = wr * 64 + fr * 16 + (lane & 15);
      af[fr] = *(const bf16x8*)(lds + pbase + ar * 256 + (kb ^ ((ar & 7) << 4)));
    }
    #pragma unroll
    for (int fr = 0; fr < 4; ++fr)
      #pragma unroll
      for (int fc = 0; fc < 4; ++fc)
        acc1[fr][fc] = __builtin_amdgcn_mfma_f32_16x16x32_bf16(
            af[fr], bfv[fc], acc1[fr][fc], 0, 0, 0);
  }
  __syncthreads();   // all LDS reads done -> safe to overwrite with h

  // GELU + b1, write h[128][256] bf16 (rows 512B, swizzled)
  {
    const int rb = wr * 64 + (lane >> 4) * 4;
    const int cb0 = wc * 64 + (lane & 15);
    #pragma unroll
    for (int fc = 0; fc < 4; ++fc) {
      int col = cb0 + fc * 16;
      float bv = b1[col];
      #pragma unroll
      for (int fr = 0; fr < 4; ++fr) {
        #pragma unroll
        for (int r = 0; r < 4; ++r) {
          int row = rb + fr * 16 + r;
          float x = acc1[fr][fc][r] + bv;
          float u2 = 1.5957691216057308f * (x + 0.044715f * x * x * x);
          float e = __expf(u2);
          x = 0.5f * x * (1.f + (1.f - 2.f / (e + 1.f)));
          *(bf16*)(lds + row * 512 + ((col * 2) ^ ((row & 7) << 4))) = (bf16)x;
        }
      }
    }
  }
  __syncthreads();

  // phase 2: out = proj + h @ W2 + b2; wave grid 4 rows x 2 cols (32x64)
  const int wr2 = wid >> 1;
  const int wc2 = wid & 1;
  f32x4 acc2[2][4] = {};
  #pragma unroll
  for (int kk = 0; kk < 8; ++kk) {
    const int kb = kk * 64 + (lane >> 4) * 16;
    bf16x8 af[2], bfv[4];
    #pragma unroll
    for (int fc = 0; fc < 4; ++fc) {
      int br = wc2 * 64 + fc * 16 + (lane & 15);
      bfv[fc] = *(const bf16x8*)(W2t + (size_t)br * 256 + kk * 32 + (lane >> 4) * 8);
    }
    #pragma unroll
    for (int fr = 0; fr < 2; ++fr) {
      int ar = wr2 * 32 + fr * 16 + (lane & 15);
      af[fr] = *(const bf16x8*)(lds + ar * 512 + (kb ^ ((ar & 7) << 4)));
    }
    #pragma unroll
    for (int fr = 0; fr < 2; ++fr)
      #pragma unroll
      for (int fc = 0; fc < 4; ++fc)
        acc2[fr][fc] = __builtin_amdgcn_mfma_f32_16x16x32_bf16(
            af[fr], bfv[fc], acc2[fr][fc], 0, 0, 0);
  }
  const int rbase = wr2 * 32 + (lane >> 4) * 4;
  const int cbase = wc2 * 64 + (lane & 15);
  #pragma unroll
  for (int fr = 0; fr < 2; ++fr) {
    #pragma unroll
    for (int fc = 0; fc < 4; ++fc) {
      int col = cbase + fc * 16;
      float bv = b2[col];
      #pragma unroll
      for (int r = 0; r < 4; ++r) {
        int row = row0 + rbase + fr * 16 + r;
        out[(size_t)row * 128 + col] =
            acc2[fr][fc][r] + bv + (float)proj[(size_t)row * 128 + col];
      }
    }
  }
}

// ---------------------------------------------------------------------------
// Bucket histogram from deg (bucket = 128 dst rows). One wave per bucket.
// ---------------------------------------------------------------------------
__global__ __launch_bounds__(256) void bucket_hist(
    const float* __restrict__ degQC, const float* __restrict__ degCQ,
    int* __restrict__ bcnt) {
  int w = (blockIdx.x * 256 + threadIdx.x) >> 6;
  int lane = threadIdx.x & 63;
  const float* deg = (w < 512) ? (degQC + (size_t)w * 128)
                               : (degCQ + (size_t)(w - 512) * 128);
  float s = deg[lane] + deg[lane + 64];
  #pragma unroll
  for (int o = 32; o; o >>= 1) s += __shfl_xor(s, o, 64);
  if (lane == 0) bcnt[w] = (int)(s + 0.5f);
}

__global__ __launch_bounds__(1024) void bucket_scan(
    const int* __restrict__ bcnt,
    int* __restrict__ baseQC, int* __restrict__ gcurQC,
    int* __restrict__ baseCQ, int* __restrict__ gcurCQ) {
  __shared__ int ss[1024];
  const int t = threadIdx.x;
  int v = (t < 512) ? bcnt[t] : 0;
  ss[t] = v;
  __syncthreads();
  for (int o = 1; o < 1024; o <<= 1) {
    int x = (t >= o) ? ss[t - o] : 0;
    __syncthreads();
    ss[t] += x;
    __syncthreads();
  }
  if (t < 512) { int e = ss[t] - v; baseQC[t] = e; gcurQC[t] = e; }
  if (t == 0) baseQC[512] = En;
  __syncthreads();
  int v2 = bcnt[512 + t];
  ss[t] = v2;
  __syncthreads();
  for (int o = 1; o < 1024; o <<= 1) {
    int x = (t >= o) ? ss[t - o] : 0;
    __syncthreads();
    ss[t] += x;
    __syncthreads();
  }
  { int e = ss[t] - v2; baseCQ[t] = e; gcurCQ[t] = e; }
  if (t == 0) baseCQ[1024] = En;
}

// ---------------------------------------------------------------------------
// Pass A: partition (src,dst) pairs into bucket-grouped ebuf (bucket=dst>>7).
// ---------------------------------------------------------------------------
#define CHUNK 4096

template <int NB>
__global__ __launch_bounds__(256) void bucketA(
    const int* __restrict__ esrc, const int* __restrict__ edst,
    int* __restrict__ gcur, uint2* __restrict__ ebuf) {
  __shared__ int lcount[NB], lexcl[NB], lbase[NB], lofs[NB];
  __shared__ int ss[256];
  __shared__ uint2 stage[CHUNK];
  const int t = threadIdx.x;
  for (int b = t; b < NB; b += 256) lcount[b] = 0;
  __syncthreads();
  const int e0 = blockIdx.x * CHUNK;
  uint2 ed[16];
  #pragma unroll
  for (int j = 0; j < 16; ++j) {
    int e = e0 + j * 256 + t;
    ed[j].x = (unsigned)esrc[e];
    ed[j].y = (unsigned)edst[e];
    atomicAdd(&lcount[ed[j].y >> 7], 1);
  }
  __syncthreads();
  constexpr int R = NB / 256;
  int c[R]; int mysum = 0;
  #pragma unroll
  for (int j = 0; j < R; ++j) { c[j] = lcount[t * R + j]; mysum += c[j]; }
  ss[t] = mysum;
  __syncthreads();
  for (int o = 1; o < 256; o <<= 1) {
    int x = (t >= o) ? ss[t - o] : 0;
    __syncthreads();
    ss[t] += x;
    __syncthreads();
  }
  int run = ss[t] - mysum;
  #pragma unroll
  for (int j = 0; j < R; ++j) { lexcl[t * R + j] = run; run += c[j]; }
  __syncthreads();
  for (int b = t; b < NB; b += 256) {
    lbase[b] = atomicAdd(&gcur[b], lcount[b]);
    lofs[b]  = lexcl[b];
  }
  __syncthreads();
  #pragma unroll
  for (int j = 0; j < 16; ++j) {
    int b = ed[j].y >> 7;
    int p = atomicAdd(&lofs[b], 1);
    stage[p] = ed[j];
  }
  __syncthreads();
  for (int i = t; i < CHUNK; i += 256) {
    uint2 v = stage[i];
    int b = v.y >> 7;
    ebuf[lbase[b] + (i - lexcl[b])] = v;
  }
}

// ---------------------------------------------------------------------------
// bucketB2: per-bucket local deg-scan -> offs; fill csr via INT LDS atomics.
// ---------------------------------------------------------------------------
__global__ __launch_bounds__(256) void bucketB2(
    const uint2* __restrict__ ebuf, const int* __restrict__ bbase,
    const float* __restrict__ degdst, int* __restrict__ offs,
    int* __restrict__ csr) {
  __shared__ int sdeg[128];
  __shared__ int lcur[128];
  const int b = blockIdx.x;
  const int t = threadIdx.x;
  const int base = bbase[b], end = bbase[b + 1];
  int myv = 0;
  if (t < 128) {
    myv = (int)(degdst[(size_t)b * 128 + t] + 0.5f);
    sdeg[t] = myv;
  }
  __syncthreads();
  for (int o = 1; o < 128; o <<= 1) {
    int x = (t < 128 && t >= o) ? sdeg[t - o] : 0;
    __syncthreads();
    if (t < 128) sdeg[t] += x;
    __syncthreads();
  }
  if (t < 128) {
    int excl = sdeg[t] - myv;
    lcur[t] = excl;
    offs[(size_t)b * 128 + t] = base + excl;
  }
  __syncthreads();
  for (int i = base + t; i < end; i += 256) {
    uint2 v = ebuf[i];
    int p = atomicAdd(&lcur[v.y & 127], 1);
    csr[base + p] = (int)v.x;
  }
}

// ---------------------------------------------------------------------------
// gather2: one wave per dst row, half-wave pairing; 8 edges in flight.
// ---------------------------------------------------------------------------
__global__ __launch_bounds__(256) void gather2(
    const bf16* __restrict__ Xn, const int* __restrict__ csr,
    const int* __restrict__ offs, const float* __restrict__ degdst,
    const float* __restrict__ gate, bf16* __restrict__ msg, int ndst) {
  int d = blockIdx.x * 4 + (threadIdx.x >> 6);
  if (d >= ndst) return;
  int lane = threadIdx.x & 63;
  int half = lane >> 5, sl = lane & 31;
  float dv = degdst[d];
  int cnt = (int)(dv + 0.5f);
  int start = offs[d];
  float a0 = 0.f, a1 = 0.f, a2 = 0.f, a3 = 0.f;
  int i = 0;
  for (; i + 8 <= cnt; i += 8) {
    int s0 = csr[start + i + half * 4 + 0];
    int s1 = csr[start + i + half * 4 + 1];
    int s2 = csr[start + i + half * 4 + 2];
    int s3 = csr[start + i + half * 4 + 3];
    bf16x4 v0 = *(const bf16x4*)(Xn + (size_t)s0 * 128 + sl * 4);
    bf16x4 v1 = *(const bf16x4*)(Xn + (size_t)s1 * 128 + sl * 4);
    bf16x4 v2 = *(const bf16x4*)(Xn + (size_t)s2 * 128 + sl * 4);
    bf16x4 v3 = *(const bf16x4*)(Xn + (size_t)s3 * 128 + sl * 4);
    a0 += (float)v0[0] + (float)v1[0] + (float)v2[0] + (float)v3[0];
    a1 += (float)v0[1] + (float)v1[1] + (float)v2[1] + (float)v3[1];
    a2 += (float)v0[2] + (float)v1[2] + (float)v2[2] + (float)v3[2];
    a3 += (float)v0[3] + (float)v1[3] + (float)v2[3] + (float)v3[3];
  }
  for (; i + 2 <= cnt; i += 2) {
    int s0 = csr[start + i + half];
    bf16x4 v0 = *(const bf16x4*)(Xn + (size_t)s0 * 128 + sl * 4);
    a0 += (float)v0[0]; a1 += (float)v0[1];
    a2 += (float)v0[2]; a3 += (float)v0[3];
  }
  if (i < cnt && half == 0) {
    int s0 = csr[start + i];
    bf16x4 v0 = *(const bf16x4*)(Xn + (size_t)s0 * 128 + sl * 4);
    a0 += (float)v0[0]; a1 += (float)v0[1];
    a2 += (float)v0[2]; a3 += (float)v0[3];
  }
  a0 += __shfl_xor(a0, 32, 64);
  a1 += __shfl_xor(a1, 32, 64);
  a2 += __shfl_xor(a2, 32, 64);
  a3 += __shfl_xor(a3, 32, 64);
  if (half == 0) {
    float sc = (dv > 0.f ? rsqrtf(dv) : 0.f) * gate[0];
    bf16x4 r;
    r[0] = (bf16)(a0 * sc); r[1] = (bf16)(a1 * sc);
    r[2] = (bf16)(a2 * sc); r[3] = (bf16)(a3 * sc);
    *(bf16x4*)(msg + (size_t)d * 128 + sl * 4) = r;
  }
}

// ---------------------------------------------------------------------------
extern "C" void kernel_launch(void* const* d_in, const int* in_sizes, int n_in,
                              void* d_out, int out_size, void* d_ws, size_t ws_size,
                              hipStream_t stream) {
  const float* H_Q        = (const float*)d_in[0];
  const float* H_C        = (const float*)d_in[1];
  const int*   eQC_src    = (const int*)d_in[2];
  const int*   eQC_dst    = (const int*)d_in[3];
  const int*   eCQ_src    = (const int*)d_in[4];
  const int*   eCQ_dst    = (const int*)d_in[5];
  const float* deg_QC_src = (const float*)d_in[6];
  const float* deg_QC_dst = (const float*)d_in[7];
  const float* deg_CQ_src = (const float*)d_in[8];
  const float* deg_CQ_dst = (const float*)d_in[9];
  const float* ln_g_Q     = (const float*)d_in[10];
  const float* ln_b_Q     = (const float*)d_in[11];
  const float* Wres_Q     = (const float*)d_in[12];
  const float* ln_g_C     = (const float*)d_in[13];
  const float* ln_b_C     = (const float*)d_in[14];
  const float* Wres_C     = (const float*)d_in[15];
  const float* Wrel_QC    = (const float*)d_in[16];
  const float* Wrel_CQ    = (const float*)d_in[17];
  const float* gate_QC    = (const float*)d_in[18];
  const float* gate_CQ    = (const float*)d_in[19];
  const float* W1_Q       = (const float*)d_in[20];
  const float* b1_Q       = (const float*)d_in[21];
  const float* W2_Q       = (const float*)d_in[22];
  const float* b2_Q       = (const float*)d_in[23];
  const float* W1_C       = (const float*)d_in[24];
  const float* b1_C       = (const float*)d_in[25];
  const float* W2_C       = (const float*)d_in[26];
  const float* b2_C       = (const float*)d_in[27];

  char* ws = (char*)d_ws;
  size_t o = 0;
  auto alloc = [&](size_t bytes) -> char* {
    char* p = ws + o;
    o += (bytes + 255) & ~(size_t)255;
    return p;
  };
  bf16* xnbQ = (bf16*)alloc((size_t)NQn * 128 * 2);
  bf16* xnbC = (bf16*)alloc((size_t)NCn * 128 * 2);
  int*  csrQC = (int*)alloc((size_t)En * 4);
  int*  csrCQ = (int*)alloc((size_t)En * 4);
  bf16* projQ = (bf16*)alloc((size_t)NQn * 128 * 2);
  bf16* projC = (bf16*)alloc((size_t)NCn * 128 * 2);
  bf16* msgQ  = (bf16*)alloc((size_t)NQn * 128 * 2);
  bf16* msgC  = (bf16*)alloc((size_t)NCn * 128 * 2);
  uint2* ebufQC = (uint2*)alloc((size_t)En * 8);
  uint2* ebufCQ = (uint2*)alloc((size_t)En * 8);
  bf16* WresQt = (bf16*)alloc(128 * 128 * 2);
  bf16* WresCt = (bf16*)alloc(128 * 128 * 2);
  bf16* WrelQCt = (bf16*)alloc(128 * 128 * 2);
  bf16* WrelCQt = (bf16*)alloc(128 * 128 * 2);
  bf16* W1Qt = (bf16*)alloc(256 * 256 * 2);
  bf16* W1Ct = (bf16*)alloc(256 * 256 * 2);
  bf16* W2Qt = (bf16*)alloc(128 * 256 * 2);
  bf16* W2Ct = (bf16*)alloc(128 * 256 * 2);
  int* bcnt   = (int*)alloc(1536 * 4);
  int* bbaseQC = (int*)alloc(513 * 4);
  int* bbaseCQ = (int*)alloc(1025 * 4);
  int* gcurQC = (int*)alloc(512 * 4);
  int* gcurCQ = (int*)alloc(1024 * 4);
  int* offsQC = (int*)alloc((size_t)NCn * 4);
  int* offsCQ = (int*)alloc((size_t)NQn * 4);

  float* outQ = (float*)d_out;
  float* outC = (float*)d_out + (size_t)NQn * 128;

  // 1. weight transpose+cast
  wtrans_all<<<dim3(256, 8), 256, 0, stream>>>(
      Wres_Q, WresQt, Wres_C, WresCt, Wrel_QC, WrelQCt, Wrel_CQ, WrelCQt,
      W1_Q, W1Qt, W1_C, W1Ct, W2_Q, W2Qt, W2_C, W2Ct);

  // 2. bucket bases + edge partition + CSR build
  bucket_hist<<<384, 256, 0, stream>>>(deg_QC_dst, deg_CQ_dst, bcnt);
  bucket_scan<<<1, 1024, 0, stream>>>(bcnt, bbaseQC, gcurQC, bbaseCQ, gcurCQ);
  bucketA<512><<<En / CHUNK, 256, 0, stream>>>(eQC_src, eQC_dst, gcurQC, ebufQC);
  bucketA<1024><<<En / CHUNK, 256, 0, stream>>>(eCQ_src, eCQ_dst, gcurCQ, ebufCQ);
  bucketB2<<<512, 256, 0, stream>>>(ebufQC, bbaseQC, deg_QC_dst, offsQC, csrQC);
  bucketB2<<<1024, 256, 0, stream>>>(ebufCQ, bbaseCQ, deg_CQ_dst, offsCQ, csrCQ);

  // 3. fused proj+xn (one H read each)
  dual_gemm<<<NQn / 128, 256, 0, stream>>>(H_Q, ln_g_Q, ln_b_Q, WresQt, WrelQCt,
                                           deg_QC_src, projQ, xnbQ);
  dual_gemm<<<NCn / 128, 256, 0, stream>>>(H_C, ln_g_C, ln_b_C, WresCt, WrelCQt,
                                           deg_CQ_src, projC, xnbC);

  // 4. gather: msgC from xnbQ (QC), msgQ from xnbC (CQ)
  gather2<<<NCn / 4, 256, 0, stream>>>(xnbQ, csrQC, offsQC, deg_QC_dst,
                                       gate_QC, msgC, NCn);
  gather2<<<NQn / 4, 256, 0, stream>>>(xnbC, csrCQ, offsCQ, deg_CQ_dst,
                                       gate_CQ, msgQ, NQn);

  // 5. fused MLP (no h round-trip)
  mlp_fused<<<NQn / 128, 512, 0, stream>>>(projQ, msgQ, W1Qt, b1_Q, W2Qt, b2_Q,
                                           outQ);
  mlp_fused<<<NCn / 128, 512, 0, stream>>>(projC, msgC, W1Ct, b1_C, W2Ct, b2_C,
                                           outC);
}

// Round 9
// 333.007 us; speedup vs baseline: 1.2036x; 1.0921x over previous
//
#include <hip/hip_runtime.h>
#include <stdint.h>

// Problem sizes (fixed by the reference)
#define NQn 131072
#define NCn 65536
#define En  1048576
// D = 128, HID = 256

typedef __bf16 bf16;
typedef __bf16 bf16x2 __attribute__((ext_vector_type(2)));
typedef __bf16 bf16x4 __attribute__((ext_vector_type(4)));
typedef __bf16 bf16x8 __attribute__((ext_vector_type(8)));
typedef float  f32x4  __attribute__((ext_vector_type(4)));

// ---------------------------------------------------------------------------
// Weight pack: fragment-major layout for MFMA B-operand.
// frag(mb, kb) = 512 elems; elem (lane,j): m = mb*16+(lane&15),
// k = kb*32+(lane>>4)*8+j. Packed offset = ((mb*(K/32)+kb)*64+lane)*8+j.
// A wave's B-fragment load is then 1KB contiguous (lane*16B).
// ---------------------------------------------------------------------------
__global__ void wtrans_all(
    const float* __restrict__ w0, bf16* __restrict__ t0,
    const float* __restrict__ w1, bf16* __restrict__ t1,
    const float* __restrict__ w2, bf16* __restrict__ t2,
    const float* __restrict__ w3, bf16* __restrict__ t3,
    const float* __restrict__ w4, bf16* __restrict__ t4,
    const float* __restrict__ w5, bf16* __restrict__ t5,
    const float* __restrict__ w6, bf16* __restrict__ t6,
    const float* __restrict__ w7, bf16* __restrict__ t7) {
  const float* W; bf16* T; int K, M;
  switch (blockIdx.y) {
    case 0: W = w0; T = t0; K = 128; M = 128; break;  // Wres_Q
    case 1: W = w1; T = t1; K = 128; M = 128; break;  // Wres_C
    case 2: W = w2; T = t2; K = 128; M = 128; break;  // Wrel_QC
    case 3: W = w3; T = t3; K = 128; M = 128; break;  // Wrel_CQ
    case 4: W = w4; T = t4; K = 256; M = 256; break;  // W1_Q
    case 5: W = w5; T = t5; K = 256; M = 256; break;  // W1_C
    case 6: W = w6; T = t6; K = 256; M = 128; break;  // W2_Q
    default: W = w7; T = t7; K = 256; M = 128; break; // W2_C
  }
  int t = blockIdx.x * 256 + threadIdx.x;
  if (t >= K * M) return;
  int KB = K >> 5;
  int frag = t >> 9, within = t & 511;
  int lane = within >> 3, j = within & 7;
  int mb = frag / KB, kb = frag % KB;
  int m = mb * 16 + (lane & 15);
  int k = kb * 32 + (lane >> 4) * 8 + j;
  T[t] = (bf16)W[k * M + m];
}

// ---------------------------------------------------------------------------
// dual_gemm: one H read -> proj = LN(H)@Wres AND xn = (H@Wrel)*deg^-1/2.
// 64-row tile, 256 threads / 4 waves (2x2), 32KB LDS -> high occupancy.
// Weights in fragment-packed layout (coalesced loads).
// ---------------------------------------------------------------------------
__global__ __launch_bounds__(256, 5) void dual_gemm(
    const float* __restrict__ H, const float* __restrict__ lng,
    const float* __restrict__ lnb, const bf16* __restrict__ Wres,
    const bf16* __restrict__ Wrel, const float* __restrict__ degsrc,
    bf16* __restrict__ proj, bf16* __restrict__ xn) {
  __shared__ __align__(16) unsigned char lds[32768];
  const int tid = threadIdx.x;
  const int row0 = blockIdx.x * 64;
  const int wid = tid >> 6, lane = tid & 63;
  const int wrow = (wid >> 1) * 32, wcol = (wid & 1) * 64;

  // stage: read H f32 (64 rows x 128 cols), LN inline, write lnh@0, hb@16384
  #pragma unroll
  for (int it = 0; it < 8; ++it) {
    int lin = it * 256 + tid;
    int r = lin >> 5;
    int c = (lin & 31) * 4;
    float4 v = *(const float4*)(H + (size_t)(row0 + r) * 128 + c);
    float s = v.x + v.y + v.z + v.w;
    #pragma unroll
    for (int o = 16; o; o >>= 1) s += __shfl_xor(s, o, 64);
    float mean = s * (1.0f / 128.0f);
    float d0 = v.x - mean, d1 = v.y - mean, d2 = v.z - mean, d3 = v.w - mean;
    float q = d0 * d0 + d1 * d1 + d2 * d2 + d3 * d3;
    #pragma unroll
    for (int o = 16; o; o >>= 1) q += __shfl_xor(q, o, 64);
    float rsv = rsqrtf(q * (1.0f / 128.0f) + 1e-5f);
    float4 gg = *(const float4*)(lng + c);
    float4 bb = *(const float4*)(lnb + c);
    bf16x4 w;
    w[0] = (bf16)(d0 * rsv * gg.x + bb.x);
    w[1] = (bf16)(d1 * rsv * gg.y + bb.y);
    w[2] = (bf16)(d2 * rsv * gg.z + bb.z);
    w[3] = (bf16)(d3 * rsv * gg.w + bb.w);
    int off = r * 256 + ((c * 2) ^ ((r & 7) << 4));
    *(bf16x4*)(lds + off) = w;
    bf16x4 rw;
    rw[0] = (bf16)v.x; rw[1] = (bf16)v.y; rw[2] = (bf16)v.z; rw[3] = (bf16)v.w;
    *(bf16x4*)(lds + 16384 + off) = rw;
  }
  __syncthreads();

  #pragma unroll
  for (int pass = 0; pass < 2; ++pass) {
    const bf16* Wp = pass ? Wrel : Wres;
    const unsigned pbase = pass ? 16384u : 0u;
    f32x4 acc[2][4] = {};
    #pragma unroll
    for (int kk = 0; kk < 4; ++kk) {
      const int kb = kk * 64 + (lane >> 4) * 16;
      bf16x8 af[2], bfv[4];
      #pragma unroll
      for (int fc = 0; fc < 4; ++fc) {
        int cblk = (wid & 1) * 4 + fc;
        bfv[fc] = *(const bf16x8*)(Wp + ((size_t)(cblk * 4 + kk) * 64 + lane) * 8);
      }
      #pragma unroll
      for (int fr = 0; fr < 2; ++fr) {
        int ar = wrow + fr * 16 + (lane & 15);
        af[fr] = *(const bf16x8*)(lds + pbase + ar * 256 + (kb ^ ((ar & 7) << 4)));
      }
      #pragma unroll
      for (int fr = 0; fr < 2; ++fr)
        #pragma unroll
        for (int fc = 0; fc < 4; ++fc)
          acc[fr][fc] = __builtin_amdgcn_mfma_f32_16x16x32_bf16(
              af[fr], bfv[fc], acc[fr][fc], 0, 0, 0);
    }
    const int rbase = row0 + wrow + (lane >> 4) * 4;
    const int cbase = wcol + (lane & 15);
    if (pass == 0) {
      #pragma unroll
      for (int fr = 0; fr < 2; ++fr)
        #pragma unroll
        for (int fc = 0; fc < 4; ++fc)
          #pragma unroll
          for (int r = 0; r < 4; ++r)
            proj[(size_t)(rbase + fr * 16 + r) * 128 + cbase + fc * 16] =
                (bf16)acc[fr][fc][r];
    } else {
      #pragma unroll
      for (int fr = 0; fr < 2; ++fr) {
        float rs[4];
        #pragma unroll
        for (int r = 0; r < 4; ++r) {
          float dv = degsrc[rbase + fr * 16 + r];
          rs[r] = dv > 0.f ? rsqrtf(dv) : 0.f;
        }
        #pragma unroll
        for (int fc = 0; fc < 4; ++fc)
          #pragma unroll
          for (int r = 0; r < 4; ++r)
            xn[(size_t)(rbase + fr * 16 + r) * 128 + cbase + fc * 16] =
                (bf16)(acc[fr][fc][r] * rs[r]);
      }
    }
  }
}

// ---------------------------------------------------------------------------
// mlp_fused: out = proj + GELU([proj|msg]@W1+b1)@W2 + b2.
// 64-row tile, 256 threads / 4 waves, 32KB LDS (A panel then h panel).
// ---------------------------------------------------------------------------
__global__ __launch_bounds__(256, 4) void mlp_fused(
    const bf16* __restrict__ proj, const bf16* __restrict__ msg,
    const bf16* __restrict__ W1p, const float* __restrict__ b1,
    const bf16* __restrict__ W2p, const float* __restrict__ b2,
    float* __restrict__ out) {
  __shared__ __align__(16) unsigned char lds[32768];
  const int tid = threadIdx.x;
  const int row0 = blockIdx.x * 64;
  const int wid = tid >> 6, lane = tid & 63;

  // stage A = [proj | msg], 64 rows x 512B (cols 0-127 = proj, 128-255 = msg)
  #pragma unroll
  for (int it = 0; it < 8; ++it) {
    int lin = it * 256 + tid;            // 0..2047 16B-chunks
    int r = lin >> 5;
    int cb = (lin & 31) * 16;            // byte col 0..511
    const bf16* src = (cb < 256) ? (proj + (size_t)(row0 + r) * 128)
                                 : (msg + (size_t)(row0 + r) * 128 - 128);
    bf16x8 v = *(const bf16x8*)((const char*)src + cb);
    *(bf16x8*)(lds + r * 512 + (cb ^ ((r & 7) << 4))) = v;
  }
  __syncthreads();

  // phase 1: h[64][256] = A @ W1 (K=256, KB=8); wave w covers cols w*64..+63
  f32x4 acc1[4][4] = {};
  #pragma unroll
  for (int kk = 0; kk < 8; ++kk) {
    const int kb = kk * 64 + (lane >> 4) * 16;   // byte offset in 512B row
    bf16x8 af[4], bfv[4];
    #pragma unroll
    for (int fc = 0; fc < 4; ++fc) {
      int cblk = wid * 4 + fc;
      bfv[fc] = *(const bf16x8*)(W1p + ((size_t)(cblk * 8 + kk) * 64 + lane) * 8);
    }
    #pragma unroll
    for (int fr = 0; fr < 4; ++fr) {
      int ar = fr * 16 + (lane & 15);
      af[fr] = *(const bf16x8*)(lds + ar * 512 + (kb ^ ((ar & 7) << 4)));
    }
    #pragma unroll
    for (int fr = 0; fr < 4; ++fr)
      #pragma unroll
      for (int fc = 0; fc < 4; ++fc)
        acc1[fr][fc] = __builtin_amdgcn_mfma_f32_16x16x32_bf16(
            af[fr], bfv[fc], acc1[fr][fc], 0, 0, 0);
  }
  __syncthreads();   // all A reads done -> safe to overwrite with h

  // GELU + b1 -> h panel (64 rows x 512B, same swizzle)
  {
    const int rb = (lane >> 4) * 4;
    const int cb0 = wid * 64 + (lane & 15);
    #pragma unroll
    for (int fc = 0; fc < 4; ++fc) {
      int col = cb0 + fc * 16;
      float bv = b1[col];
      #pragma unroll
      for (int fr = 0; fr < 4; ++fr) {
        #pragma unroll
        for (int r = 0; r < 4; ++r) {
          int row = rb + fr * 16 + r;
          float x = acc1[fr][fc][r] + bv;
          float u2 = 1.5957691216057308f * (x + 0.044715f * x * x * x);
          float e = __expf(u2);
          x = 0.5f * x * (1.f + (1.f - 2.f / (e + 1.f)));
          *(bf16*)(lds + row * 512 + ((col * 2) ^ ((row & 7) << 4))) = (bf16)x;
        }
      }
    }
  }
  __syncthreads();

  // phase 2: out = proj + h @ W2 + b2 (K=256, KB=8); wave grid 2x2 (32x64)
  const int wrow2 = (wid >> 1) * 32;
  const int wcol2 = (wid & 1) * 64;
  f32x4 acc2[2][4] = {};
  #pragma unroll
  for (int kk = 0; kk < 8; ++kk) {
    const int kb = kk * 64 + (lane >> 4) * 16;
    bf16x8 af[2], bfv[4];
    #pragma unroll
    for (int fc = 0; fc < 4; ++fc) {
      int cblk = (wid & 1) * 4 + fc;
      bfv[fc] = *(const bf16x8*)(W2p + ((size_t)(cblk * 8 + kk) * 64 + lane) * 8);
    }
    #pragma unroll
    for (int fr = 0; fr < 2; ++fr) {
      int ar = wrow2 + fr * 16 + (lane & 15);
      af[fr] = *(const bf16x8*)(lds + ar * 512 + (kb ^ ((ar & 7) << 4)));
    }
    #pragma unroll
    for (int fr = 0; fr < 2; ++fr)
      #pragma unroll
      for (int fc = 0; fc < 4; ++fc)
        acc2[fr][fc] = __builtin_amdgcn_mfma_f32_16x16x32_bf16(
            af[fr], bfv[fc], acc2[fr][fc], 0, 0, 0);
  }
  const int rbase = wrow2 + (lane >> 4) * 4;
  const int cbase = wcol2 + (lane & 15);
  #pragma unroll
  for (int fr = 0; fr < 2; ++fr) {
    #pragma unroll
    for (int fc = 0; fc < 4; ++fc) {
      int col = cbase + fc * 16;
      float bv = b2[col];
      #pragma unroll
      for (int r = 0; r < 4; ++r) {
        int row = row0 + rbase + fr * 16 + r;
        out[(size_t)row * 128 + col] =
            acc2[fr][fc][r] + bv + (float)proj[(size_t)row * 128 + col];
      }
    }
  }
}

// ---------------------------------------------------------------------------
// Bucket histogram from deg (bucket = 128 dst rows). One wave per bucket.
// ---------------------------------------------------------------------------
__global__ __launch_bounds__(256) void bucket_hist(
    const float* __restrict__ degQC, const float* __restrict__ degCQ,
    int* __restrict__ bcnt) {
  int w = (blockIdx.x * 256 + threadIdx.x) >> 6;
  int lane = threadIdx.x & 63;
  const float* deg = (w < 512) ? (degQC + (size_t)w * 128)
                               : (degCQ + (size_t)(w - 512) * 128);
  float s = deg[lane] + deg[lane + 64];
  #pragma unroll
  for (int o = 32; o; o >>= 1) s += __shfl_xor(s, o, 64);
  if (lane == 0) bcnt[w] = (int)(s + 0.5f);
}

__global__ __launch_bounds__(1024) void bucket_scan(
    const int* __restrict__ bcnt,
    int* __restrict__ baseQC, int* __restrict__ gcurQC,
    int* __restrict__ baseCQ, int* __restrict__ gcurCQ) {
  __shared__ int ss[1024];
  const int t = threadIdx.x;
  int v = (t < 512) ? bcnt[t] : 0;
  ss[t] = v;
  __syncthreads();
  for (int o = 1; o < 1024; o <<= 1) {
    int x = (t >= o) ? ss[t - o] : 0;
    __syncthreads();
    ss[t] += x;
    __syncthreads();
  }
  if (t < 512) { int e = ss[t] - v; baseQC[t] = e; gcurQC[t] = e; }
  if (t == 0) baseQC[512] = En;
  __syncthreads();
  int v2 = bcnt[512 + t];
  ss[t] = v2;
  __syncthreads();
  for (int o = 1; o < 1024; o <<= 1) {
    int x = (t >= o) ? ss[t - o] : 0;
    __syncthreads();
    ss[t] += x;
    __syncthreads();
  }
  { int e = ss[t] - v2; baseCQ[t] = e; gcurCQ[t] = e; }
  if (t == 0) baseCQ[1024] = En;
}

// ---------------------------------------------------------------------------
// Pass A: partition (src,dst) pairs into bucket-grouped ebuf (bucket=dst>>7).
// ---------------------------------------------------------------------------
#define CHUNK 4096

template <int NB>
__global__ __launch_bounds__(256) void bucketA(
    const int* __restrict__ esrc, const int* __restrict__ edst,
    int* __restrict__ gcur, uint2* __restrict__ ebuf) {
  __shared__ int lcount[NB], lexcl[NB], lbase[NB], lofs[NB];
  __shared__ int ss[256];
  __shared__ uint2 stage[CHUNK];
  const int t = threadIdx.x;
  for (int b = t; b < NB; b += 256) lcount[b] = 0;
  __syncthreads();
  const int e0 = blockIdx.x * CHUNK;
  uint2 ed[16];
  #pragma unroll
  for (int j = 0; j < 16; ++j) {
    int e = e0 + j * 256 + t;
    ed[j].x = (unsigned)esrc[e];
    ed[j].y = (unsigned)edst[e];
    atomicAdd(&lcount[ed[j].y >> 7], 1);
  }
  __syncthreads();
  constexpr int R = NB / 256;
  int c[R]; int mysum = 0;
  #pragma unroll
  for (int j = 0; j < R; ++j) { c[j] = lcount[t * R + j]; mysum += c[j]; }
  ss[t] = mysum;
  __syncthreads();
  for (int o = 1; o < 256; o <<= 1) {
    int x = (t >= o) ? ss[t - o] : 0;
    __syncthreads();
    ss[t] += x;
    __syncthreads();
  }
  int run = ss[t] - mysum;
  #pragma unroll
  for (int j = 0; j < R; ++j) { lexcl[t * R + j] = run; run += c[j]; }
  __syncthreads();
  for (int b = t; b < NB; b += 256) {
    lbase[b] = atomicAdd(&gcur[b], lcount[b]);
    lofs[b]  = lexcl[b];
  }
  __syncthreads();
  #pragma unroll
  for (int j = 0; j < 16; ++j) {
    int b = ed[j].y >> 7;
    int p = atomicAdd(&lofs[b], 1);
    stage[p] = ed[j];
  }
  __syncthreads();
  for (int i = t; i < CHUNK; i += 256) {
    uint2 v = stage[i];
    int b = v.y >> 7;
    ebuf[lbase[b] + (i - lexcl[b])] = v;
  }
}

// ---------------------------------------------------------------------------
// bucketB2: per-bucket local deg-scan -> offs; fill csr via INT LDS atomics.
// ---------------------------------------------------------------------------
__global__ __launch_bounds__(256) void bucketB2(
    const uint2* __restrict__ ebuf, const int* __restrict__ bbase,
    const float* __restrict__ degdst, int* __restrict__ offs,
    int* __restrict__ csr) {
  __shared__ int sdeg[128];
  __shared__ int lcur[128];
  const int b = blockIdx.x;
  const int t = threadIdx.x;
  const int base = bbase[b], end = bbase[b + 1];
  int myv = 0;
  if (t < 128) {
    myv = (int)(degdst[(size_t)b * 128 + t] + 0.5f);
    sdeg[t] = myv;
  }
  __syncthreads();
  for (int o = 1; o < 128; o <<= 1) {
    int x = (t < 128 && t >= o) ? sdeg[t - o] : 0;
    __syncthreads();
    if (t < 128) sdeg[t] += x;
    __syncthreads();
  }
  if (t < 128) {
    int excl = sdeg[t] - myv;
    lcur[t] = excl;
    offs[(size_t)b * 128 + t] = base + excl;
  }
  __syncthreads();
  for (int i = base + t; i < end; i += 256) {
    uint2 v = ebuf[i];
    int p = atomicAdd(&lcur[v.y & 127], 1);
    csr[base + p] = (int)v.x;
  }
}

// ---------------------------------------------------------------------------
// gather2: one wave per dst row, half-wave pairing; 8 edges in flight.
// ---------------------------------------------------------------------------
__global__ __launch_bounds__(256) void gather2(
    const bf16* __restrict__ Xn, const int* __restrict__ csr,
    const int* __restrict__ offs, const float* __restrict__ degdst,
    const float* __restrict__ gate, bf16* __restrict__ msg, int ndst) {
  int d = blockIdx.x * 4 + (threadIdx.x >> 6);
  if (d >= ndst) return;
  int lane = threadIdx.x & 63;
  int half = lane >> 5, sl = lane & 31;
  float dv = degdst[d];
  int cnt = (int)(dv + 0.5f);
  int start = offs[d];
  float a0 = 0.f, a1 = 0.f, a2 = 0.f, a3 = 0.f;
  int i = 0;
  for (; i + 8 <= cnt; i += 8) {
    int s0 = csr[start + i + half * 4 + 0];
    int s1 = csr[start + i + half * 4 + 1];
    int s2 = csr[start + i + half * 4 + 2];
    int s3 = csr[start + i + half * 4 + 3];
    bf16x4 v0 = *(const bf16x4*)(Xn + (size_t)s0 * 128 + sl * 4);
    bf16x4 v1 = *(const bf16x4*)(Xn + (size_t)s1 * 128 + sl * 4);
    bf16x4 v2 = *(const bf16x4*)(Xn + (size_t)s2 * 128 + sl * 4);
    bf16x4 v3 = *(const bf16x4*)(Xn + (size_t)s3 * 128 + sl * 4);
    a0 += (float)v0[0] + (float)v1[0] + (float)v2[0] + (float)v3[0];
    a1 += (float)v0[1] + (float)v1[1] + (float)v2[1] + (float)v3[1];
    a2 += (float)v0[2] + (float)v1[2] + (float)v2[2] + (float)v3[2];
    a3 += (float)v0[3] + (float)v1[3] + (float)v2[3] + (float)v3[3];
  }
  for (; i + 2 <= cnt; i += 2) {
    int s0 = csr[start + i + half];
    bf16x4 v0 = *(const bf16x4*)(Xn + (size_t)s0 * 128 + sl * 4);
    a0 += (float)v0[0]; a1 += (float)v0[1];
    a2 += (float)v0[2]; a3 += (float)v0[3];
  }
  if (i < cnt && half == 0) {
    int s0 = csr[start + i];
    bf16x4 v0 = *(const bf16x4*)(Xn + (size_t)s0 * 128 + sl * 4);
    a0 += (float)v0[0]; a1 += (float)v0[1];
    a2 += (float)v0[2]; a3 += (float)v0[3];
  }
  a0 += __shfl_xor(a0, 32, 64);
  a1 += __shfl_xor(a1, 32, 64);
  a2 += __shfl_xor(a2, 32, 64);
  a3 += __shfl_xor(a3, 32, 64);
  if (half == 0) {
    float sc = (dv > 0.f ? rsqrtf(dv) : 0.f) * gate[0];
    bf16x4 r;
    r[0] = (bf16)(a0 * sc); r[1] = (bf16)(a1 * sc);
    r[2] = (bf16)(a2 * sc); r[3] = (bf16)(a3 * sc);
    *(bf16x4*)(msg + (size_t)d * 128 + sl * 4) = r;
  }
}

// ---------------------------------------------------------------------------
extern "C" void kernel_launch(void* const* d_in, const int* in_sizes, int n_in,
                              void* d_out, int out_size, void* d_ws, size_t ws_size,
                              hipStream_t stream) {
  const float* H_Q        = (const float*)d_in[0];
  const float* H_C        = (const float*)d_in[1];
  const int*   eQC_src    = (const int*)d_in[2];
  const int*   eQC_dst    = (const int*)d_in[3];
  const int*   eCQ_src    = (const int*)d_in[4];
  const int*   eCQ_dst    = (const int*)d_in[5];
  const float* deg_QC_src = (const float*)d_in[6];
  const float* deg_QC_dst = (const float*)d_in[7];
  const float* deg_CQ_src = (const float*)d_in[8];
  const float* deg_CQ_dst = (const float*)d_in[9];
  const float* ln_g_Q     = (const float*)d_in[10];
  const float* ln_b_Q     = (const float*)d_in[11];
  const float* Wres_Q     = (const float*)d_in[12];
  const float* ln_g_C     = (const float*)d_in[13];
  const float* ln_b_C     = (const float*)d_in[14];
  const float* Wres_C     = (const float*)d_in[15];
  const float* Wrel_QC    = (const float*)d_in[16];
  const float* Wrel_CQ    = (const float*)d_in[17];
  const float* gate_QC    = (const float*)d_in[18];
  const float* gate_CQ    = (const float*)d_in[19];
  const float* W1_Q       = (const float*)d_in[20];
  const float* b1_Q       = (const float*)d_in[21];
  const float* W2_Q       = (const float*)d_in[22];
  const float* b2_Q       = (const float*)d_in[23];
  const float* W1_C       = (const float*)d_in[24];
  const float* b1_C       = (const float*)d_in[25];
  const float* W2_C       = (const float*)d_in[26];
  const float* b2_C       = (const float*)d_in[27];

  char* ws = (char*)d_ws;
  size_t o = 0;
  auto alloc = [&](size_t bytes) -> char* {
    char* p = ws + o;
    o += (bytes + 255) & ~(size_t)255;
    return p;
  };
  bf16* xnbQ = (bf16*)alloc((size_t)NQn * 128 * 2);
  bf16* xnbC = (bf16*)alloc((size_t)NCn * 128 * 2);
  int*  csrQC = (int*)alloc((size_t)En * 4);
  int*  csrCQ = (int*)alloc((size_t)En * 4);
  bf16* projQ = (bf16*)alloc((size_t)NQn * 128 * 2);
  bf16* projC = (bf16*)alloc((size_t)NCn * 128 * 2);
  bf16* msgQ  = (bf16*)alloc((size_t)NQn * 128 * 2);
  bf16* msgC  = (bf16*)alloc((size_t)NCn * 128 * 2);
  uint2* ebufQC = (uint2*)alloc((size_t)En * 8);
  uint2* ebufCQ = (uint2*)alloc((size_t)En * 8);
  bf16* WresQt = (bf16*)alloc(128 * 128 * 2);
  bf16* WresCt = (bf16*)alloc(128 * 128 * 2);
  bf16* WrelQCt = (bf16*)alloc(128 * 128 * 2);
  bf16* WrelCQt = (bf16*)alloc(128 * 128 * 2);
  bf16* W1Qt = (bf16*)alloc(256 * 256 * 2);
  bf16* W1Ct = (bf16*)alloc(256 * 256 * 2);
  bf16* W2Qt = (bf16*)alloc(128 * 256 * 2);
  bf16* W2Ct = (bf16*)alloc(128 * 256 * 2);
  int* bcnt   = (int*)alloc(1536 * 4);
  int* bbaseQC = (int*)alloc(513 * 4);
  int* bbaseCQ = (int*)alloc(1025 * 4);
  int* gcurQC = (int*)alloc(512 * 4);
  int* gcurCQ = (int*)alloc(1024 * 4);
  int* offsQC = (int*)alloc((size_t)NCn * 4);
  int* offsCQ = (int*)alloc((size_t)NQn * 4);

  float* outQ = (float*)d_out;
  float* outC = (float*)d_out + (size_t)NQn * 128;

  // 1. weight pack (fragment-major) + bf16 cast
  wtrans_all<<<dim3(256, 8), 256, 0, stream>>>(
      Wres_Q, WresQt, Wres_C, WresCt, Wrel_QC, WrelQCt, Wrel_CQ, WrelCQt,
      W1_Q, W1Qt, W1_C, W1Ct, W2_Q, W2Qt, W2_C, W2Ct);

  // 2. bucket bases + edge partition + CSR build
  bucket_hist<<<384, 256, 0, stream>>>(deg_QC_dst, deg_CQ_dst, bcnt);
  bucket_scan<<<1, 1024, 0, stream>>>(bcnt, bbaseQC, gcurQC, bbaseCQ, gcurCQ);
  bucketA<512><<<En / CHUNK, 256, 0, stream>>>(eQC_src, eQC_dst, gcurQC, ebufQC);
  bucketA<1024><<<En / CHUNK, 256, 0, stream>>>(eCQ_src, eCQ_dst, gcurCQ, ebufCQ);
  bucketB2<<<512, 256, 0, stream>>>(ebufQC, bbaseQC, deg_QC_dst, offsQC, csrQC);
  bucketB2<<<1024, 256, 0, stream>>>(ebufCQ, bbaseCQ, deg_CQ_dst, offsCQ, csrCQ);

  // 3. fused proj+xn (one H read each)
  dual_gemm<<<NQn / 64, 256, 0, stream>>>(H_Q, ln_g_Q, ln_b_Q, WresQt, WrelQCt,
                                          deg_QC_src, projQ, xnbQ);
  dual_gemm<<<NCn / 64, 256, 0, stream>>>(H_C, ln_g_C, ln_b_C, WresCt, WrelCQt,
                                          deg_CQ_src, projC, xnbC);

  // 4. gather: msgC from xnbQ (QC), msgQ from xnbC (CQ)
  gather2<<<NCn / 4, 256, 0, stream>>>(xnbQ, csrQC, offsQC, deg_QC_dst,
                                       gate_QC, msgC, NCn);
  gather2<<<NQn / 4, 256, 0, stream>>>(xnbC, csrCQ, offsCQ, deg_CQ_dst,
                                       gate_CQ, msgQ, NQn);

  // 5. fused MLP (no h round-trip)
  mlp_fused<<<NQn / 64, 256, 0, stream>>>(projQ, msgQ, W1Qt, b1_Q, W2Qt, b2_Q,
                                          outQ);
  mlp_fused<<<NCn / 64, 256, 0, stream>>>(projC, msgC, W1Ct, b1_C, W2Ct, b2_C,
                                          outC);
}

// Round 10
// 273.714 us; speedup vs baseline: 1.4643x; 1.2166x over previous
//
#include <hip/hip_runtime.h>
#include <stdint.h>

// Problem sizes (fixed by the reference)
#define NQn 131072
#define NCn 65536
#define En  1048576
// D = 128, HID = 256

typedef __bf16 bf16;
typedef __bf16 bf16x2 __attribute__((ext_vector_type(2)));
typedef __bf16 bf16x4 __attribute__((ext_vector_type(4)));
typedef __bf16 bf16x8 __attribute__((ext_vector_type(8)));
typedef float  f32x4  __attribute__((ext_vector_type(4)));

// ---------------------------------------------------------------------------
// Weight pack: fragment-major layout for MFMA B-operand (see R8 notes).
// ---------------------------------------------------------------------------
__global__ void wtrans_all(
    const float* __restrict__ w0, bf16* __restrict__ t0,
    const float* __restrict__ w1, bf16* __restrict__ t1,
    const float* __restrict__ w2, bf16* __restrict__ t2,
    const float* __restrict__ w3, bf16* __restrict__ t3,
    const float* __restrict__ w4, bf16* __restrict__ t4,
    const float* __restrict__ w5, bf16* __restrict__ t5,
    const float* __restrict__ w6, bf16* __restrict__ t6,
    const float* __restrict__ w7, bf16* __restrict__ t7) {
  const float* W; bf16* T; int K, M;
  switch (blockIdx.y) {
    case 0: W = w0; T = t0; K = 128; M = 128; break;  // Wres_Q
    case 1: W = w1; T = t1; K = 128; M = 128; break;  // Wres_C
    case 2: W = w2; T = t2; K = 128; M = 128; break;  // Wrel_QC
    case 3: W = w3; T = t3; K = 128; M = 128; break;  // Wrel_CQ
    case 4: W = w4; T = t4; K = 256; M = 256; break;  // W1_Q
    case 5: W = w5; T = t5; K = 256; M = 256; break;  // W1_C
    case 6: W = w6; T = t6; K = 256; M = 128; break;  // W2_Q
    default: W = w7; T = t7; K = 256; M = 128; break; // W2_C
  }
  int t = blockIdx.x * 256 + threadIdx.x;
  if (t >= K * M) return;
  int KB = K >> 5;
  int frag = t >> 9, within = t & 511;
  int lane = within >> 3, j = within & 7;
  int mb = frag / KB, kb = frag % KB;
  int m = mb * 16 + (lane & 15);
  int k = kb * 32 + (lane >> 4) * 8 + j;
  T[t] = (bf16)W[k * M + m];
}

// ---------------------------------------------------------------------------
// dual_gemm2: merged Q+C. One H read -> proj = LN(H)@Wres AND
// xn = (H@Wrel)*deg^-1/2. 64-row tile, 4 waves, 32KB LDS.
// Epilogue staged through LDS -> bf16x8 coalesced stores.
// ---------------------------------------------------------------------------
__global__ __launch_bounds__(256, 5) void dual_gemm2(
    const float* __restrict__ HQ, const float* __restrict__ lngQ,
    const float* __restrict__ lnbQ, const bf16* __restrict__ WresQ,
    const bf16* __restrict__ WrelQ, const float* __restrict__ degQ,
    bf16* __restrict__ projQ, bf16* __restrict__ xnQ, int splitQ,
    const float* __restrict__ HC, const float* __restrict__ lngC,
    const float* __restrict__ lnbC, const bf16* __restrict__ WresC,
    const bf16* __restrict__ WrelC, const float* __restrict__ degC,
    bf16* __restrict__ projC, bf16* __restrict__ xnC) {
  __shared__ __align__(16) unsigned char lds[32768];
  const float *H, *lng, *lnb, *degsrc;
  const bf16 *Wres, *Wrel;
  bf16 *proj, *xn;
  int bid = blockIdx.x;
  if (bid < splitQ) {
    H = HQ; lng = lngQ; lnb = lnbQ; Wres = WresQ; Wrel = WrelQ;
    degsrc = degQ; proj = projQ; xn = xnQ;
  } else {
    bid -= splitQ;
    H = HC; lng = lngC; lnb = lnbC; Wres = WresC; Wrel = WrelC;
    degsrc = degC; proj = projC; xn = xnC;
  }
  const int tid = threadIdx.x;
  const int row0 = bid * 64;
  const int wid = tid >> 6, lane = tid & 63;
  const int wrow = (wid >> 1) * 32, wcol = (wid & 1) * 64;

  // stage: read H f32, LN inline, write lnh@0, hb@16384 (rows 256B, swizzled)
  #pragma unroll
  for (int it = 0; it < 8; ++it) {
    int lin = it * 256 + tid;
    int r = lin >> 5;
    int c = (lin & 31) * 4;
    float4 v = *(const float4*)(H + (size_t)(row0 + r) * 128 + c);
    float s = v.x + v.y + v.z + v.w;
    #pragma unroll
    for (int o = 16; o; o >>= 1) s += __shfl_xor(s, o, 64);
    float mean = s * (1.0f / 128.0f);
    float d0 = v.x - mean, d1 = v.y - mean, d2 = v.z - mean, d3 = v.w - mean;
    float q = d0 * d0 + d1 * d1 + d2 * d2 + d3 * d3;
    #pragma unroll
    for (int o = 16; o; o >>= 1) q += __shfl_xor(q, o, 64);
    float rsv = rsqrtf(q * (1.0f / 128.0f) + 1e-5f);
    float4 gg = *(const float4*)(lng + c);
    float4 bb = *(const float4*)(lnb + c);
    bf16x4 w;
    w[0] = (bf16)(d0 * rsv * gg.x + bb.x);
    w[1] = (bf16)(d1 * rsv * gg.y + bb.y);
    w[2] = (bf16)(d2 * rsv * gg.z + bb.z);
    w[3] = (bf16)(d3 * rsv * gg.w + bb.w);
    int off = r * 256 + ((c * 2) ^ ((r & 7) << 4));
    *(bf16x4*)(lds + off) = w;
    bf16x4 rw;
    rw[0] = (bf16)v.x; rw[1] = (bf16)v.y; rw[2] = (bf16)v.z; rw[3] = (bf16)v.w;
    *(bf16x4*)(lds + 16384 + off) = rw;
  }
  __syncthreads();

  const int rloc = wrow + (lane >> 4) * 4;        // local row base of acc
  const int cloc = wcol + (lane & 15);            // local col base of acc

  // pass 0: proj = lnh @ Wres
  {
    f32x4 acc[2][4] = {};
    #pragma unroll
    for (int kk = 0; kk < 4; ++kk) {
      const int kb = kk * 64 + (lane >> 4) * 16;
      bf16x8 af[2], bfv[4];
      #pragma unroll
      for (int fc = 0; fc < 4; ++fc) {
        int cblk = (wid & 1) * 4 + fc;
        bfv[fc] = *(const bf16x8*)(Wres + ((size_t)(cblk * 4 + kk) * 64 + lane) * 8);
      }
      #pragma unroll
      for (int fr = 0; fr < 2; ++fr) {
        int ar = wrow + fr * 16 + (lane & 15);
        af[fr] = *(const bf16x8*)(lds + ar * 256 + (kb ^ ((ar & 7) << 4)));
      }
      #pragma unroll
      for (int fr = 0; fr < 2; ++fr)
        #pragma unroll
        for (int fc = 0; fc < 4; ++fc)
          acc[fr][fc] = __builtin_amdgcn_mfma_f32_16x16x32_bf16(
              af[fr], bfv[fc], acc[fr][fc], 0, 0, 0);
    }
    __syncthreads();   // lnh reads done -> panel0 reusable
    #pragma unroll
    for (int fr = 0; fr < 2; ++fr)
      #pragma unroll
      for (int fc = 0; fc < 4; ++fc)
        #pragma unroll
        for (int r = 0; r < 4; ++r) {
          int row = rloc + fr * 16 + r;
          int colb = (cloc + fc * 16) * 2;
          *(bf16*)(lds + row * 256 + (colb ^ ((row & 7) << 4))) =
              (bf16)acc[fr][fc][r];
        }
  }

  // pass 1: xn = (hb @ Wrel) * invsqrt(deg)   (hb panel untouched)
  {
    f32x4 acc[2][4] = {};
    #pragma unroll
    for (int kk = 0; kk < 4; ++kk) {
      const int kb = kk * 64 + (lane >> 4) * 16;
      bf16x8 af[2], bfv[4];
      #pragma unroll
      for (int fc = 0; fc < 4; ++fc) {
        int cblk = (wid & 1) * 4 + fc;
        bfv[fc] = *(const bf16x8*)(Wrel + ((size_t)(cblk * 4 + kk) * 64 + lane) * 8);
      }
      #pragma unroll
      for (int fr = 0; fr < 2; ++fr) {
        int ar = wrow + fr * 16 + (lane & 15);
        af[fr] = *(const bf16x8*)(lds + 16384 + ar * 256 + (kb ^ ((ar & 7) << 4)));
      }
      #pragma unroll
      for (int fr = 0; fr < 2; ++fr)
        #pragma unroll
        for (int fc = 0; fc < 4; ++fc)
          acc[fr][fc] = __builtin_amdgcn_mfma_f32_16x16x32_bf16(
              af[fr], bfv[fc], acc[fr][fc], 0, 0, 0);
    }
    __syncthreads();   // hb reads done -> panel1 reusable
    #pragma unroll
    for (int fr = 0; fr < 2; ++fr) {
      float rs[4];
      #pragma unroll
      for (int r = 0; r < 4; ++r) {
        float dv = degsrc[row0 + rloc + fr * 16 + r];
        rs[r] = dv > 0.f ? rsqrtf(dv) : 0.f;
      }
      #pragma unroll
      for (int fc = 0; fc < 4; ++fc)
        #pragma unroll
        for (int r = 0; r < 4; ++r) {
          int row = rloc + fr * 16 + r;
          int colb = (cloc + fc * 16) * 2;
          *(bf16*)(lds + 16384 + row * 256 + (colb ^ ((row & 7) << 4))) =
              (bf16)(acc[fr][fc][r] * rs[r]);
        }
    }
  }
  __syncthreads();

  // coalesced stores: 16KB proj tile + 16KB xn tile, bf16x8 per chunk
  #pragma unroll
  for (int it = 0; it < 8; ++it) {
    int lin = it * 256 + tid;          // 0..2047; first 1024 = proj
    int pb = (lin < 1024) ? 0 : 16384;
    bf16* dst = (lin < 1024) ? proj : xn;
    int chunk = lin & 1023;
    int r = chunk >> 4;
    int cb = (chunk & 15) * 16;
    bf16x8 v = *(const bf16x8*)(lds + pb + r * 256 + (cb ^ ((r & 7) << 4)));
    *(bf16x8*)((char*)(dst + (size_t)(row0 + r) * 128) + cb) = v;
  }
}

// ---------------------------------------------------------------------------
// mlp_fused2: merged Q+C. out = proj + GELU([proj|msg]@W1+b1)@W2 + b2.
// 64-row tile, 4 waves, 32KB LDS (A panel then h panel). f32 out is
// 64B-coalesced already.
// ---------------------------------------------------------------------------
__global__ __launch_bounds__(256, 4) void mlp_fused2(
    const bf16* __restrict__ projQ, const bf16* __restrict__ msgQ,
    const bf16* __restrict__ W1Q, const float* __restrict__ b1Q,
    const bf16* __restrict__ W2Q, const float* __restrict__ b2Q,
    float* __restrict__ outQ, int splitQ,
    const bf16* __restrict__ projC, const bf16* __restrict__ msgC,
    const bf16* __restrict__ W1C, const float* __restrict__ b1C,
    const bf16* __restrict__ W2C, const float* __restrict__ b2C,
    float* __restrict__ outC) {
  __shared__ __align__(16) unsigned char lds[32768];
  const bf16 *proj, *msg, *W1p, *W2p;
  const float *b1, *b2;
  float* out;
  int bid = blockIdx.x;
  if (bid < splitQ) {
    proj = projQ; msg = msgQ; W1p = W1Q; b1 = b1Q; W2p = W2Q; b2 = b2Q; out = outQ;
  } else {
    bid -= splitQ;
    proj = projC; msg = msgC; W1p = W1C; b1 = b1C; W2p = W2C; b2 = b2C; out = outC;
  }
  const int tid = threadIdx.x;
  const int row0 = bid * 64;
  const int wid = tid >> 6, lane = tid & 63;

  // stage A = [proj | msg], 64 rows x 512B
  #pragma unroll
  for (int it = 0; it < 8; ++it) {
    int lin = it * 256 + tid;
    int r = lin >> 5;
    int cb = (lin & 31) * 16;
    const bf16* src = (cb < 256) ? (proj + (size_t)(row0 + r) * 128)
                                 : (msg + (size_t)(row0 + r) * 128 - 128);
    bf16x8 v = *(const bf16x8*)((const char*)src + cb);
    *(bf16x8*)(lds + r * 512 + (cb ^ ((r & 7) << 4))) = v;
  }
  __syncthreads();

  // phase 1: h[64][256] = A @ W1 (K=256); wave w covers cols w*64..+63
  f32x4 acc1[4][4] = {};
  #pragma unroll
  for (int kk = 0; kk < 8; ++kk) {
    const int kb = kk * 64 + (lane >> 4) * 16;
    bf16x8 af[4], bfv[4];
    #pragma unroll
    for (int fc = 0; fc < 4; ++fc) {
      int cblk = wid * 4 + fc;
      bfv[fc] = *(const bf16x8*)(W1p + ((size_t)(cblk * 8 + kk) * 64 + lane) * 8);
    }
    #pragma unroll
    for (int fr = 0; fr < 4; ++fr) {
      int ar = fr * 16 + (lane & 15);
      af[fr] = *(const bf16x8*)(lds + ar * 512 + (kb ^ ((ar & 7) << 4)));
    }
    #pragma unroll
    for (int fr = 0; fr < 4; ++fr)
      #pragma unroll
      for (int fc = 0; fc < 4; ++fc)
        acc1[fr][fc] = __builtin_amdgcn_mfma_f32_16x16x32_bf16(
            af[fr], bfv[fc], acc1[fr][fc], 0, 0, 0);
  }
  __syncthreads();

  // GELU + b1 -> h panel (64 rows x 512B, same swizzle)
  {
    const int rb = (lane >> 4) * 4;
    const int cb0 = wid * 64 + (lane & 15);
    #pragma unroll
    for (int fc = 0; fc < 4; ++fc) {
      int col = cb0 + fc * 16;
      float bv = b1[col];
      #pragma unroll
      for (int fr = 0; fr < 4; ++fr) {
        #pragma unroll
        for (int r = 0; r < 4; ++r) {
          int row = rb + fr * 16 + r;
          float x = acc1[fr][fc][r] + bv;
          float u2 = 1.5957691216057308f * (x + 0.044715f * x * x * x);
          float e = __expf(u2);
          x = 0.5f * x * (1.f + (1.f - 2.f / (e + 1.f)));
          *(bf16*)(lds + row * 512 + ((col * 2) ^ ((row & 7) << 4))) = (bf16)x;
        }
      }
    }
  }
  __syncthreads();

  // phase 2: out = proj + h @ W2 + b2; wave grid 2x2 (32x64)
  const int wrow2 = (wid >> 1) * 32;
  const int wcol2 = (wid & 1) * 64;
  f32x4 acc2[2][4] = {};
  #pragma unroll
  for (int kk = 0; kk < 8; ++kk) {
    const int kb = kk * 64 + (lane >> 4) * 16;
    bf16x8 af[2], bfv[4];
    #pragma unroll
    for (int fc = 0; fc < 4; ++fc) {
      int cblk = (wid & 1) * 4 + fc;
      bfv[fc] = *(const bf16x8*)(W2p + ((size_t)(cblk * 8 + kk) * 64 + lane) * 8);
    }
    #pragma unroll
    for (int fr = 0; fr < 2; ++fr) {
      int ar = wrow2 + fr * 16 + (lane & 15);
      af[fr] = *(const bf16x8*)(lds + ar * 512 + (kb ^ ((ar & 7) << 4)));
    }
    #pragma unroll
    for (int fr = 0; fr < 2; ++fr)
      #pragma unroll
      for (int fc = 0; fc < 4; ++fc)
        acc2[fr][fc] = __builtin_amdgcn_mfma_f32_16x16x32_bf16(
            af[fr], bfv[fc], acc2[fr][fc], 0, 0, 0);
  }
  const int rbase = wrow2 + (lane >> 4) * 4;
  const int cbase = wcol2 + (lane & 15);
  #pragma unroll
  for (int fr = 0; fr < 2; ++fr) {
    #pragma unroll
    for (int fc = 0; fc < 4; ++fc) {
      int col = cbase + fc * 16;
      float bv = b2[col];
      #pragma unroll
      for (int r = 0; r < 4; ++r) {
        int row = row0 + rbase + fr * 16 + r;
        out[(size_t)row * 128 + col] =
            acc2[fr][fc][r] + bv + (float)proj[(size_t)row * 128 + col];
      }
    }
  }
}

// ---------------------------------------------------------------------------
// Bucket histogram + scan (bucket = 128 dst rows). bcnt: [512 QC][1024 CQ]
// ---------------------------------------------------------------------------
__global__ __launch_bounds__(256) void bucket_hist(
    const float* __restrict__ degQC, const float* __restrict__ degCQ,
    int* __restrict__ bcnt) {
  int w = (blockIdx.x * 256 + threadIdx.x) >> 6;
  int lane = threadIdx.x & 63;
  const float* deg = (w < 512) ? (degQC + (size_t)w * 128)
                               : (degCQ + (size_t)(w - 512) * 128);
  float s = deg[lane] + deg[lane + 64];
  #pragma unroll
  for (int o = 32; o; o >>= 1) s += __shfl_xor(s, o, 64);
  if (lane == 0) bcnt[w] = (int)(s + 0.5f);
}

__global__ __launch_bounds__(1024) void bucket_scan(
    const int* __restrict__ bcnt,
    int* __restrict__ baseQC, int* __restrict__ gcurQC,
    int* __restrict__ baseCQ, int* __restrict__ gcurCQ) {
  __shared__ int ss[1024];
  const int t = threadIdx.x;
  int v = (t < 512) ? bcnt[t] : 0;
  ss[t] = v;
  __syncthreads();
  for (int o = 1; o < 1024; o <<= 1) {
    int x = (t >= o) ? ss[t - o] : 0;
    __syncthreads();
    ss[t] += x;
    __syncthreads();
  }
  if (t < 512) { int e = ss[t] - v; baseQC[t] = e; gcurQC[t] = e; }
  if (t == 0) baseQC[512] = En;
  __syncthreads();
  int v2 = bcnt[512 + t];
  ss[t] = v2;
  __syncthreads();
  for (int o = 1; o < 1024; o <<= 1) {
    int x = (t >= o) ? ss[t - o] : 0;
    __syncthreads();
    ss[t] += x;
    __syncthreads();
  }
  { int e = ss[t] - v2; baseCQ[t] = e; gcurCQ[t] = e; }
  if (t == 0) baseCQ[1024] = En;
}

// ---------------------------------------------------------------------------
// bucketA2: merged Q+C edge partition (bucket = dst>>7). NB=1024 shared;
// QC uses only 512 active buckets (guarded).
// ---------------------------------------------------------------------------
#define CHUNK 4096

__global__ __launch_bounds__(256) void bucketA2(
    const int* __restrict__ esrcQ, const int* __restrict__ edstQ,
    int* __restrict__ gcurQ, uint2* __restrict__ ebufQ, int splitQ,
    const int* __restrict__ esrcC, const int* __restrict__ edstC,
    int* __restrict__ gcurC, uint2* __restrict__ ebufC) {
  constexpr int NB = 1024;
  __shared__ int lcount[NB], lexcl[NB], lbase[NB], lofs[NB];
  __shared__ int ss[256];
  __shared__ uint2 stage[CHUNK];
  const int* esrc; const int* edst; int* gcur; uint2* ebuf; int nb;
  int bid = blockIdx.x;
  if (bid < splitQ) { esrc = esrcQ; edst = edstQ; gcur = gcurQ; ebuf = ebufQ; nb = 512; }
  else { bid -= splitQ; esrc = esrcC; edst = edstC; gcur = gcurC; ebuf = ebufC; nb = 1024; }
  const int t = threadIdx.x;
  for (int b = t; b < NB; b += 256) lcount[b] = 0;
  __syncthreads();
  const int e0 = bid * CHUNK;
  uint2 ed[16];
  #pragma unroll
  for (int j = 0; j < 16; ++j) {
    int e = e0 + j * 256 + t;
    ed[j].x = (unsigned)esrc[e];
    ed[j].y = (unsigned)edst[e];
    atomicAdd(&lcount[ed[j].y >> 7], 1);
  }
  __syncthreads();
  int c[4]; int mysum = 0;
  #pragma unroll
  for (int j = 0; j < 4; ++j) { c[j] = lcount[t * 4 + j]; mysum += c[j]; }
  ss[t] = mysum;
  __syncthreads();
  for (int o = 1; o < 256; o <<= 1) {
    int x = (t >= o) ? ss[t - o] : 0;
    __syncthreads();
    ss[t] += x;
    __syncthreads();
  }
  int run = ss[t] - mysum;
  #pragma unroll
  for (int j = 0; j < 4; ++j) { lexcl[t * 4 + j] = run; run += c[j]; }
  __syncthreads();
  for (int b = t; b < NB; b += 256) {
    lbase[b] = (b < nb && lcount[b]) ? atomicAdd(&gcur[b], lcount[b]) : 0;
    lofs[b]  = lexcl[b];
  }
  __syncthreads();
  #pragma unroll
  for (int j = 0; j < 16; ++j) {
    int b = ed[j].y >> 7;
    int p = atomicAdd(&lofs[b], 1);
    stage[p] = ed[j];
  }
  __syncthreads();
  for (int i = t; i < CHUNK; i += 256) {
    uint2 v = stage[i];
    int b = v.y >> 7;
    ebuf[lbase[b] + (i - lexcl[b])] = v;
  }
}

// ---------------------------------------------------------------------------
// bucketB22: merged Q+C. Per-bucket deg-scan -> offs; fill csr via INT LDS
// atomics (csr window contiguous, L2-hot).
// ---------------------------------------------------------------------------
__global__ __launch_bounds__(256) void bucketB22(
    const uint2* __restrict__ ebufQ, const int* __restrict__ bbaseQ,
    const float* __restrict__ degQ, int* __restrict__ offsQ,
    int* __restrict__ csrQ, int splitQ,
    const uint2* __restrict__ ebufC, const int* __restrict__ bbaseC,
    const float* __restrict__ degC, int* __restrict__ offsC,
    int* __restrict__ csrC) {
  __shared__ int sdeg[128];
  __shared__ int lcur[128];
  const uint2* ebuf; const int* bbase; const float* degdst; int* offs; int* csr;
  int b = blockIdx.x;
  if (b < splitQ) { ebuf = ebufQ; bbase = bbaseQ; degdst = degQ; offs = offsQ; csr = csrQ; }
  else { b -= splitQ; ebuf = ebufC; bbase = bbaseC; degdst = degC; offs = offsC; csr = csrC; }
  const int t = threadIdx.x;
  const int base = bbase[b], end = bbase[b + 1];
  int myv = 0;
  if (t < 128) {
    myv = (int)(degdst[(size_t)b * 128 + t] + 0.5f);
    sdeg[t] = myv;
  }
  __syncthreads();
  for (int o = 1; o < 128; o <<= 1) {
    int x = (t < 128 && t >= o) ? sdeg[t - o] : 0;
    __syncthreads();
    if (t < 128) sdeg[t] += x;
    __syncthreads();
  }
  if (t < 128) {
    int excl = sdeg[t] - myv;
    lcur[t] = excl;
    offs[(size_t)b * 128 + t] = base + excl;
  }
  __syncthreads();
  for (int i = base + t; i < end; i += 256) {
    uint2 v = ebuf[i];
    int p = atomicAdd(&lcur[v.y & 127], 1);
    csr[base + p] = (int)v.x;
  }
}

// ---------------------------------------------------------------------------
// gather22: merged Q+C. One wave per dst row, half-wave pairing, 8 edges
// in flight.
// ---------------------------------------------------------------------------
__global__ __launch_bounds__(256) void gather22(
    const bf16* __restrict__ XnQ, const int* __restrict__ csrQ,
    const int* __restrict__ offsQ, const float* __restrict__ degQ,
    const float* __restrict__ gateQ, bf16* __restrict__ msgOutC, int splitC,
    const bf16* __restrict__ XnC, const int* __restrict__ csrC,
    const int* __restrict__ offsC, const float* __restrict__ degC,
    const float* __restrict__ gateC, bf16* __restrict__ msgOutQ) {
  const bf16* Xn; const int* csr; const int* offs; const float* degdst;
  const float* gate; bf16* msg;
  int bid = blockIdx.x;
  if (bid < splitC) {
    Xn = XnQ; csr = csrQ; offs = offsQ; degdst = degQ; gate = gateQ; msg = msgOutC;
  } else {
    bid -= splitC;
    Xn = XnC; csr = csrC; offs = offsC; degdst = degC; gate = gateC; msg = msgOutQ;
  }
  int d = bid * 4 + (threadIdx.x >> 6);
  int lane = threadIdx.x & 63;
  int half = lane >> 5, sl = lane & 31;
  float dv = degdst[d];
  int cnt = (int)(dv + 0.5f);
  int start = offs[d];
  float a0 = 0.f, a1 = 0.f, a2 = 0.f, a3 = 0.f;
  int i = 0;
  for (; i + 8 <= cnt; i += 8) {
    int s0 = csr[start + i + half * 4 + 0];
    int s1 = csr[start + i + half * 4 + 1];
    int s2 = csr[start + i + half * 4 + 2];
    int s3 = csr[start + i + half * 4 + 3];
    bf16x4 v0 = *(const bf16x4*)(Xn + (size_t)s0 * 128 + sl * 4);
    bf16x4 v1 = *(const bf16x4*)(Xn + (size_t)s1 * 128 + sl * 4);
    bf16x4 v2 = *(const bf16x4*)(Xn + (size_t)s2 * 128 + sl * 4);
    bf16x4 v3 = *(const bf16x4*)(Xn + (size_t)s3 * 128 + sl * 4);
    a0 += (float)v0[0] + (float)v1[0] + (float)v2[0] + (float)v3[0];
    a1 += (float)v0[1] + (float)v1[1] + (float)v2[1] + (float)v3[1];
    a2 += (float)v0[2] + (float)v1[2] + (float)v2[2] + (float)v3[2];
    a3 += (float)v0[3] + (float)v1[3] + (float)v2[3] + (float)v3[3];
  }
  for (; i + 2 <= cnt; i += 2) {
    int s0 = csr[start + i + half];
    bf16x4 v0 = *(const bf16x4*)(Xn + (size_t)s0 * 128 + sl * 4);
    a0 += (float)v0[0]; a1 += (float)v0[1];
    a2 += (float)v0[2]; a3 += (float)v0[3];
  }
  if (i < cnt && half == 0) {
    int s0 = csr[start + i];
    bf16x4 v0 = *(const bf16x4*)(Xn + (size_t)s0 * 128 + sl * 4);
    a0 += (float)v0[0]; a1 += (float)v0[1];
    a2 += (float)v0[2]; a3 += (float)v0[3];
  }
  a0 += __shfl_xor(a0, 32, 64);
  a1 += __shfl_xor(a1, 32, 64);
  a2 += __shfl_xor(a2, 32, 64);
  a3 += __shfl_xor(a3, 32, 64);
  if (half == 0) {
    float sc = (dv > 0.f ? rsqrtf(dv) : 0.f) * gate[0];
    bf16x4 r;
    r[0] = (bf16)(a0 * sc); r[1] = (bf16)(a1 * sc);
    r[2] = (bf16)(a2 * sc); r[3] = (bf16)(a3 * sc);
    *(bf16x4*)(msg + (size_t)d * 128 + sl * 4) = r;
  }
}

// ---------------------------------------------------------------------------
extern "C" void kernel_launch(void* const* d_in, const int* in_sizes, int n_in,
                              void* d_out, int out_size, void* d_ws, size_t ws_size,
                              hipStream_t stream) {
  const float* H_Q        = (const float*)d_in[0];
  const float* H_C        = (const float*)d_in[1];
  const int*   eQC_src    = (const int*)d_in[2];
  const int*   eQC_dst    = (const int*)d_in[3];
  const int*   eCQ_src    = (const int*)d_in[4];
  const int*   eCQ_dst    = (const int*)d_in[5];
  const float* deg_QC_src = (const float*)d_in[6];
  const float* deg_QC_dst = (const float*)d_in[7];
  const float* deg_CQ_src = (const float*)d_in[8];
  const float* deg_CQ_dst = (const float*)d_in[9];
  const float* ln_g_Q     = (const float*)d_in[10];
  const float* ln_b_Q     = (const float*)d_in[11];
  const float* Wres_Q     = (const float*)d_in[12];
  const float* ln_g_C     = (const float*)d_in[13];
  const float* ln_b_C     = (const float*)d_in[14];
  const float* Wres_C     = (const float*)d_in[15];
  const float* Wrel_QC    = (const float*)d_in[16];
  const float* Wrel_CQ    = (const float*)d_in[17];
  const float* gate_QC    = (const float*)d_in[18];
  const float* gate_CQ    = (const float*)d_in[19];
  const float* W1_Q       = (const float*)d_in[20];
  const float* b1_Q       = (const float*)d_in[21];
  const float* W2_Q       = (const float*)d_in[22];
  const float* b2_Q       = (const float*)d_in[23];
  const float* W1_C       = (const float*)d_in[24];
  const float* b1_C       = (const float*)d_in[25];
  const float* W2_C       = (const float*)d_in[26];
  const float* b2_C       = (const float*)d_in[27];

  char* ws = (char*)d_ws;
  size_t o = 0;
  auto alloc = [&](size_t bytes) -> char* {
    char* p = ws + o;
    o += (bytes + 255) & ~(size_t)255;
    return p;
  };
  bf16* xnbQ = (bf16*)alloc((size_t)NQn * 128 * 2);
  bf16* xnbC = (bf16*)alloc((size_t)NCn * 128 * 2);
  int*  csrQC = (int*)alloc((size_t)En * 4);
  int*  csrCQ = (int*)alloc((size_t)En * 4);
  bf16* projQ = (bf16*)alloc((size_t)NQn * 128 * 2);
  bf16* projC = (bf16*)alloc((size_t)NCn * 128 * 2);
  bf16* msgQ  = (bf16*)alloc((size_t)NQn * 128 * 2);
  bf16* msgC  = (bf16*)alloc((size_t)NCn * 128 * 2);
  uint2* ebufQC = (uint2*)alloc((size_t)En * 8);
  uint2* ebufCQ = (uint2*)alloc((size_t)En * 8);
  bf16* WresQt = (bf16*)alloc(128 * 128 * 2);
  bf16* WresCt = (bf16*)alloc(128 * 128 * 2);
  bf16* WrelQCt = (bf16*)alloc(128 * 128 * 2);
  bf16* WrelCQt = (bf16*)alloc(128 * 128 * 2);
  bf16* W1Qt = (bf16*)alloc(256 * 256 * 2);
  bf16* W1Ct = (bf16*)alloc(256 * 256 * 2);
  bf16* W2Qt = (bf16*)alloc(128 * 256 * 2);
  bf16* W2Ct = (bf16*)alloc(128 * 256 * 2);
  int* bcnt   = (int*)alloc(1536 * 4);
  int* bbaseQC = (int*)alloc(513 * 4);
  int* bbaseCQ = (int*)alloc(1025 * 4);
  int* gcurQC = (int*)alloc(512 * 4);
  int* gcurCQ = (int*)alloc(1024 * 4);
  int* offsQC = (int*)alloc((size_t)NCn * 4);
  int* offsCQ = (int*)alloc((size_t)NQn * 4);

  float* outQ = (float*)d_out;
  float* outC = (float*)d_out + (size_t)NQn * 128;

  // 1. weight pack (fragment-major) + bf16 cast
  wtrans_all<<<dim3(256, 8), 256, 0, stream>>>(
      Wres_Q, WresQt, Wres_C, WresCt, Wrel_QC, WrelQCt, Wrel_CQ, WrelCQt,
      W1_Q, W1Qt, W1_C, W1Ct, W2_Q, W2Qt, W2_C, W2Ct);

  // 2. bucket bases + merged edge partition + merged CSR build
  bucket_hist<<<384, 256, 0, stream>>>(deg_QC_dst, deg_CQ_dst, bcnt);
  bucket_scan<<<1, 1024, 0, stream>>>(bcnt, bbaseQC, gcurQC, bbaseCQ, gcurCQ);
  bucketA2<<<512, 256, 0, stream>>>(eQC_src, eQC_dst, gcurQC, ebufQC, 256,
                                    eCQ_src, eCQ_dst, gcurCQ, ebufCQ);
  bucketB22<<<1536, 256, 0, stream>>>(ebufQC, bbaseQC, deg_QC_dst, offsQC,
                                      csrQC, 512,
                                      ebufCQ, bbaseCQ, deg_CQ_dst, offsCQ,
                                      csrCQ);

  // 3. merged fused proj+xn
  dual_gemm2<<<NQn / 64 + NCn / 64, 256, 0, stream>>>(
      H_Q, ln_g_Q, ln_b_Q, WresQt, WrelQCt, deg_QC_src, projQ, xnbQ, NQn / 64,
      H_C, ln_g_C, ln_b_C, WresCt, WrelCQt, deg_CQ_src, projC, xnbC);

  // 4. merged gather
  gather22<<<NCn / 4 + NQn / 4, 256, 0, stream>>>(
      xnbQ, csrQC, offsQC, deg_QC_dst, gate_QC, msgC, NCn / 4,
      xnbC, csrCQ, offsCQ, deg_CQ_dst, gate_CQ, msgQ);

  // 5. merged fused MLP
  mlp_fused2<<<NQn / 64 + NCn / 64, 256, 0, stream>>>(
      projQ, msgQ, W1Qt, b1_Q, W2Qt, b2_Q, outQ, NQn / 64,
      projC, msgC, W1Ct, b1_C, W2Ct, b2_C, outC);
}